// Round 2
// baseline (2044.509 us; speedup 1.0000x reference)
//
#include <hip/hip_runtime.h>
#include <hip/hip_bf16.h>
#include <cstddef>

#define F_ACC  1
#define F_RELU 2

typedef unsigned short u16;
typedef short bf16x8 __attribute__((ext_vector_type(8)));
typedef float f32x4 __attribute__((ext_vector_type(4)));
typedef unsigned short u16x8 __attribute__((ext_vector_type(8)));

__device__ inline u16 f2b(float x) {
    union { float f; unsigned u; } c; c.f = x;
    unsigned r = c.u + 0x7FFF + ((c.u >> 16) & 1);
    return (u16)(r >> 16);
}

// ---------------- MFMA GEMM: fp32 A (row-major [M,K]) x packed bf16 Wt ([256][K],
// n-major) -> fp32 C [M,256], flags = F_ACC / F_RELU, bias optional ----------------
// Pipelined: next K-tile's global loads are issued into registers before the MFMA
// phase so HBM latency hides under ds_read+MFMA (T14 async-stage split). 1-D grid
// with XCD-chunked bijective swizzle so the two N-blocks sharing A rows share an
// XCD L2 (T1, m204 formula).
#define GTM 128
#define GTN 128
#define GBK 64
#define LDA 72   // 64 + 8 pad (u16 elems); row stride 144B = 16B-aligned, 2-way-bank free

__global__ __launch_bounds__(256, 2) void gemm_mfma(
    const float* __restrict__ A, const u16* __restrict__ Wt,
    const float* __restrict__ bias, float* __restrict__ C,
    int M, int K, int flags)
{
    __shared__ u16 As[GTM][LDA];
    __shared__ u16 Bs[GTN][LDA];
    const int tid  = threadIdx.x;

    // XCD-chunked bijective block swizzle (8 XCDs): consecutive wg stay on one XCD
    const int nwg = gridDim.x;
    const int q   = nwg >> 3, r = nwg & 7;
    const int xcd = blockIdx.x & 7, lin = blockIdx.x >> 3;
    const int wg  = (xcd < r ? xcd * (q + 1) : r * (q + 1) + (xcd - r) * q) + lin;
    const int bm  = (wg >> 1) * GTM;
    const int bn  = (wg & 1) * GTN;

    const int wave = tid >> 6, lane = tid & 63;
    const int wm   = (wave >> 1) * 64, wn = (wave & 1) * 64;
    const int l16  = lane & 15, lq = lane >> 4;
    const int sr   = tid >> 1;          // 0..127
    const int sk   = (tid & 1) * 32;    // 0 or 32

    f32x4 acc[4][4] = {};

    const int  arow = bm + sr;
    const bool aok  = arow < M;
    const float* Ap = A + (size_t)(aok ? arow : 0) * K + sk;
    const u16*   Wp = Wt + (size_t)(bn + sr) * K + sk;

    float4 pa[8];
    float4 pb[4];

    // prologue: tile 0 loads into registers
#pragma unroll
    for (int i = 0; i < 8; ++i)
        pa[i] = aok ? *(const float4*)(Ap + i * 4) : make_float4(0.f, 0.f, 0.f, 0.f);
#pragma unroll
    for (int i = 0; i < 4; ++i)
        pb[i] = *(const float4*)(Wp + i * 8);

    const int nt = K / GBK;
    for (int t = 0; t < nt; ++t) {
        // ---- convert + LDS write of tile t (compiler inserts counted vmcnt waits) ----
#pragma unroll
        for (int i = 0; i < 4; ++i) {
            float4 a = pa[2 * i], b = pa[2 * i + 1];
            u16x8 v;
            v[0] = f2b(a.x); v[1] = f2b(a.y); v[2] = f2b(a.z); v[3] = f2b(a.w);
            v[4] = f2b(b.x); v[5] = f2b(b.y); v[6] = f2b(b.z); v[7] = f2b(b.w);
            *(u16x8*)&As[sr][sk + i * 8] = v;
        }
#pragma unroll
        for (int i = 0; i < 4; ++i)
            *(float4*)&Bs[sr][sk + i * 8] = pb[i];

        // ---- issue tile t+1 loads NOW; they stay in flight across barrier+MFMA ----
        if (t + 1 < nt) {
            const float* Ap2 = Ap + (t + 1) * GBK;
            const u16*   Wp2 = Wp + (t + 1) * GBK;
#pragma unroll
            for (int i = 0; i < 8; ++i)
                pa[i] = aok ? *(const float4*)(Ap2 + i * 4) : make_float4(0.f, 0.f, 0.f, 0.f);
#pragma unroll
            for (int i = 0; i < 4; ++i)
                pb[i] = *(const float4*)(Wp2 + i * 8);
        }
        __syncthreads();

        // ---- MFMA on tile t ----
#pragma unroll
        for (int kk = 0; kk < GBK; kk += 32) {
            bf16x8 af[4], bfr[4];
#pragma unroll
            for (int mt = 0; mt < 4; ++mt)
                af[mt] = *(const bf16x8*)&As[wm + mt * 16 + l16][kk + lq * 8];
#pragma unroll
            for (int nt2 = 0; nt2 < 4; ++nt2)
                bfr[nt2] = *(const bf16x8*)&Bs[wn + nt2 * 16 + l16][kk + lq * 8];
#pragma unroll
            for (int mt = 0; mt < 4; ++mt)
#pragma unroll
                for (int nt2 = 0; nt2 < 4; ++nt2)
                    acc[mt][nt2] = __builtin_amdgcn_mfma_f32_16x16x32_bf16(
                        af[mt], bfr[nt2], acc[mt][nt2], 0, 0, 0);
        }
        __syncthreads();
    }

    // epilogue: C/D layout col=lane&15, row=(lane>>4)*4+reg
#pragma unroll
    for (int mt = 0; mt < 4; ++mt) {
#pragma unroll
        for (int nt2 = 0; nt2 < 4; ++nt2) {
            int col = bn + wn + nt2 * 16 + l16;
            float bv = (bias != nullptr) ? bias[col] : 0.f;
#pragma unroll
            for (int rr = 0; rr < 4; ++rr) {
                int row = bm + wm + mt * 16 + lq * 4 + rr;
                if (row >= M) continue;
                float v = acc[mt][nt2][rr] + bv;
                size_t o = (size_t)row * 256 + col;
                if (flags & F_ACC) v += C[o];
                if (flags & F_RELU) v = fmaxf(v, 0.f);
                C[o] = v;
            }
        }
    }
}

// W [Kpart,256] fp32 (+optional addend) -> out[n][koff+k] bf16, out is [256][Ktot]
__global__ void pack_wt(const float* __restrict__ W, const float* __restrict__ Wadd,
                        u16* __restrict__ out, int Kpart, int Ktot, int koff)
{
    int idx = blockIdx.x * blockDim.x + threadIdx.x;
    if (idx >= 256 * Kpart) return;
    int n = idx / Kpart, k = idx % Kpart;
    float v = W[(size_t)k * 256 + n];
    if (Wadd) v += Wadd[(size_t)k * 256 + n];
    out[(size_t)n * Ktot + koff + k] = f2b(v);
}

__global__ void vsum_bias(const float* __restrict__ a, const float* __restrict__ b,
                          float* __restrict__ o, int n)
{
    int i = blockIdx.x * blockDim.x + threadIdx.x;
    if (i < n) o[i] = a[i] + b[i];
}

// ---------------- CSR construction ----------------

__global__ void count_edges(const int* __restrict__ dst, int E, int* __restrict__ cnt)
{
    int i = blockIdx.x * blockDim.x + threadIdx.x;
    if (i < E) atomicAdd(&cnt[dst[i]], 1);
}

__global__ void make_inv(const int* __restrict__ cnt, float* __restrict__ inv, int n)
{
    int i = blockIdx.x * blockDim.x + threadIdx.x;
    if (i < n) {
        int c = cnt[i];
        inv[i] = 1.0f / (float)(c > 1 ? c : 1);
    }
}

__global__ void scan1(const int* __restrict__ cnt, int n, int* __restrict__ rowptr,
                      int* __restrict__ bsums)
{
    __shared__ int tmp[256];
    int i = blockIdx.x * 256 + threadIdx.x;
    tmp[threadIdx.x] = (i < n) ? cnt[i] : 0;
    __syncthreads();
    for (int off = 1; off < 256; off <<= 1) {
        int t = (threadIdx.x >= (unsigned)off) ? tmp[threadIdx.x - off] : 0;
        __syncthreads();
        tmp[threadIdx.x] += t;
        __syncthreads();
    }
    if (i < n) rowptr[i + 1] = tmp[threadIdx.x];
    if (threadIdx.x == 255) bsums[blockIdx.x] = tmp[255];
}

__global__ void scan2(int* __restrict__ bsums, int nb)
{
    __shared__ int tmp[256];
    __shared__ int carry;
    if (threadIdx.x == 0) carry = 0;
    __syncthreads();
    for (int base = 0; base < nb; base += 256) {
        int i = base + threadIdx.x;
        tmp[threadIdx.x] = (i < nb) ? bsums[i] : 0;
        __syncthreads();
        for (int off = 1; off < 256; off <<= 1) {
            int t = (threadIdx.x >= (unsigned)off) ? tmp[threadIdx.x - off] : 0;
            __syncthreads();
            tmp[threadIdx.x] += t;
            __syncthreads();
        }
        int c = carry;
        if (i < nb) bsums[i] = tmp[threadIdx.x] + c;
        __syncthreads();
        if (threadIdx.x == 255) carry = c + tmp[255];
        __syncthreads();
    }
}

__global__ void scan3(int* __restrict__ rowptr, const int* __restrict__ bsums, int n)
{
    int i = blockIdx.x * 256 + threadIdx.x;
    if (i == 0) rowptr[0] = 0;
    if (i < n && blockIdx.x > 0) rowptr[i + 1] += bsums[blockIdx.x - 1];
}

__global__ void csr_fill(const int* __restrict__ src, const int* __restrict__ dst, int E,
                         const int* __restrict__ rowptr, int* __restrict__ fillc,
                         int* __restrict__ col)
{
    int e = blockIdx.x * blockDim.x + threadIdx.x;
    if (e < E) {
        int d = dst[e];
        int p = atomicAdd(&fillc[d], 1);
        col[rowptr[d] + p] = src[e];
    }
}

// ---------------- CSR mean-aggregation (gather, no atomics, fp32) ----------------
__global__ __launch_bounds__(256) void gather_mean(
    const float* __restrict__ X, const int* __restrict__ rowptr,
    const int* __restrict__ col, const float* __restrict__ inv,
    float* __restrict__ out, int Nd)
{
    long long gid = (long long)blockIdx.x * blockDim.x + threadIdx.x;
    int row = (int)(gid >> 6);
    if (row >= Nd) return;
    int c = (threadIdx.x & 63) << 2;
    int e0 = rowptr[row], e1 = rowptr[row + 1];
    float4 acc = make_float4(0.f, 0.f, 0.f, 0.f);
    int e = e0;
    for (; e + 1 < e1; e += 2) {           // 2-way unroll: independent loads
        int s0 = col[e], s1 = col[e + 1];  // wave-uniform
        float4 v0 = *(const float4*)(X + (size_t)s0 * 256 + c);
        float4 v1 = *(const float4*)(X + (size_t)s1 * 256 + c);
        acc.x += v0.x + v1.x; acc.y += v0.y + v1.y;
        acc.z += v0.z + v1.z; acc.w += v0.w + v1.w;
    }
    if (e < e1) {
        int s = col[e];
        float4 v = *(const float4*)(X + (size_t)s * 256 + c);
        acc.x += v.x; acc.y += v.y; acc.z += v.z; acc.w += v.w;
    }
    float sc = inv[row];
    acc.x *= sc; acc.y *= sc; acc.z *= sc; acc.w *= sc;
    *(float4*)(out + (size_t)row * 256 + c) = acc;
}

// ---------------- attention / pooling (segmented, no atomics) ----------------

// scores[i] = dot(s_att[i,:], c_att[batch[i],:]) — one wave per row
__global__ __launch_bounds__(256) void scores_kernel(
    const float* __restrict__ s_att, const float* __restrict__ c_att,
    const int* __restrict__ batch, float* __restrict__ scores, int Ns)
{
    long long gid = (long long)blockIdx.x * blockDim.x + threadIdx.x;
    int row = (int)(gid >> 6);
    if (row >= Ns) return;
    int lane = threadIdx.x & 63;
    int b = batch[row];
    float4 s4 = *(const float4*)(s_att + (size_t)row * 256 + (lane << 2));
    float4 c4 = *(const float4*)(c_att + (size_t)b * 256 + (lane << 2));
    float p = s4.x * c4.x + s4.y * c4.y + s4.z * c4.z + s4.w * c4.w;
#pragma unroll
    for (int off = 32; off > 0; off >>= 1) p += __shfl_down(p, off, 64);
    if (lane == 0) scores[row] = p;
}

// batch_s is sorted: rp[b] = first row with batch >= b; rp[B] = Ns
__global__ void batch_bounds(const int* __restrict__ batch, int Ns, int B,
                             int* __restrict__ rp)
{
    int i = blockIdx.x * blockDim.x + threadIdx.x;
    if (i > Ns) return;
    if (i == 0) {
        int b1 = batch[0];
        for (int b = 0; b <= b1; ++b) rp[b] = 0;
    } else if (i == Ns) {
        int b0 = batch[Ns - 1];
        for (int b = b0 + 1; b <= B; ++b) rp[b] = Ns;
    } else {
        int b0 = batch[i - 1], b1 = batch[i];
        for (int b = b0 + 1; b <= b1; ++b) rp[b] = i;
    }
}

// one block per graph: softmax over its contiguous rows + weighted column sum
// scores is overwritten with exp(score - max) as scratch
__global__ __launch_bounds__(256) void pool_kernel(
    float* __restrict__ scores, const float* __restrict__ xs,
    const int* __restrict__ rp, float* __restrict__ g)
{
    __shared__ float red[256];
    const int b = blockIdx.x, tid = threadIdx.x;
    const int r0 = rp[b], r1 = rp[b + 1];
    if (r0 >= r1) { g[(size_t)b * 256 + tid] = 0.f; return; }  // uniform per block
    // phase 1: max
    float m = -3.4e38f;
    for (int r = r0 + tid; r < r1; r += 256) m = fmaxf(m, scores[r]);
    red[tid] = m; __syncthreads();
    for (int s = 128; s > 0; s >>= 1) {
        if (tid < s) red[tid] = fmaxf(red[tid], red[tid + s]);
        __syncthreads();
    }
    m = red[0]; __syncthreads();
    // phase 2: exp + sum (each thread owns its strided rows; write e in place)
    float sum = 0.f;
    for (int r = r0 + tid; r < r1; r += 256) {
        float e = __expf(scores[r] - m);
        scores[r] = e;
        sum += e;
    }
    red[tid] = sum; __syncthreads();
    for (int s = 128; s > 0; s >>= 1) {
        if (tid < s) red[tid] += red[tid + s];
        __syncthreads();
    }
    const float inv = 1.0f / red[0];
    __syncthreads();
    // phase 3: column accumulation, thread = column
    float acc = 0.f;
    for (int r = r0; r < r1; ++r)
        acc += scores[r] * xs[(size_t)r * 256 + tid];
    g[(size_t)b * 256 + tid] = acc * inv;
}

__global__ void z_kernel(const float* __restrict__ ch, const float* __restrict__ g,
                         float* __restrict__ z, int B, int H)
{
    int i = blockIdx.x * blockDim.x + threadIdx.x;
    if (i >= B * H) return;
    int b = i / H, c = i % H;
    float cv = ch[i], gv = g[i];
    float* zr = z + (size_t)b * 4 * H;
    zr[c]         = cv;
    zr[H + c]     = gv;
    zr[2 * H + c] = fabsf(cv - gv);
    zr[3 * H + c] = cv * gv;
}

__global__ void out_kernel(const float* __restrict__ h, const float* __restrict__ W2,
                           const float* __restrict__ b2, float* __restrict__ out, int B, int H)
{
    int i = blockIdx.x * blockDim.x + threadIdx.x;
    if (i >= B * 2) return;
    int b = i >> 1, j = i & 1;
    float s = b2[j];
    const float* hr = h + (size_t)b * H;
    for (int k = 0; k < H; ++k) s += hr[k] * W2[k * 2 + j];
    out[i] = s;
}

extern "C" void kernel_launch(void* const* d_in, const int* in_sizes, int n_in,
                              void* d_out, int out_size, void* d_ws, size_t ws_size,
                              hipStream_t stream)
{
    const float* x_s    = (const float*)d_in[0];
    const float* x_n    = (const float*)d_in[1];
    const float* claim  = (const float*)d_in[2];
    const int*   batch_s= (const int*)d_in[3];
    const int*   src_ss = (const int*)d_in[4];
    const int*   dst_ss = (const int*)d_in[5];
    const int*   src_sn = (const int*)d_in[6];
    const int*   dst_sn = (const int*)d_in[7];
    const int*   src_ns = (const int*)d_in[8];
    const int*   dst_ns = (const int*)d_in[9];
    const float* W_ps   = (const float*)d_in[10];
    const float* b_ps   = (const float*)d_in[11];
    const float* W_pn   = (const float*)d_in[12];
    const float* b_pn   = (const float*)d_in[13];
    const float* W_pc   = (const float*)d_in[14];
    const float* b_pc   = (const float*)d_in[15];
    const float* conv_Wl= (const float*)d_in[16];
    const float* conv_bl= (const float*)d_in[17];
    const float* conv_Wr= (const float*)d_in[18];
    const float* W_attc = (const float*)d_in[19];
    const float* W_atts = (const float*)d_in[20];
    const float* W1     = (const float*)d_in[21];
    const float* b1     = (const float*)d_in[22];
    const float* W2     = (const float*)d_in[23];
    const float* b2     = (const float*)d_in[24];

    const int in_dim = 768, H = 256;
    const int Ns  = in_sizes[0] / in_dim;
    const int Ne  = in_sizes[1] / in_dim;
    const int B   = in_sizes[2] / in_dim;
    const int Ess = in_sizes[4];
    const int Esn = in_sizes[6];
    const int Ens = in_sizes[8];
    const int L   = in_sizes[16] / (3 * H * H);
    const int Nmax = (Ns > Ne) ? Ns : Ne;
    const int nb_max = (Nmax + 255) / 256;
    const size_t HH = (size_t)H * H;

    float* ws = (float*)d_ws;
    size_t off = 0;
    auto alloc = [&](size_t n) { float* p = ws + off; off += (n + 63) & ~(size_t)63; return p; };
    float* xs_a  = alloc((size_t)Ns * H);
    float* xs_b  = alloc((size_t)Ns * H);
    float* xn_a  = alloc((size_t)Ne * H);
    float* xn_b  = alloc((size_t)Ne * H);
    float* m_big = alloc((size_t)Nmax * H);   // gather output / s_att at the end
    float* ch    = alloc((size_t)B * H);
    float* c_att = alloc((size_t)B * H);
    float* bsum0 = alloc(H);
    float* bsum1 = alloc(H);
    // packed bf16 weights (u16, [256][K] n-major); sizes in float-slots = elems/2
    u16* wt_ps   = (u16*)alloc((size_t)256 * 768 / 2);
    u16* wt_pn   = (u16*)alloc((size_t)256 * 768 / 2);
    u16* wt_pc   = (u16*)alloc((size_t)256 * 768 / 2);
    u16* wt_l0_a = (u16*)alloc(HH / 2);
    u16* wt_l1_a = (u16*)alloc(HH / 2);
    u16* wt_l2_a = (u16*)alloc(HH / 2);
    u16* wt_rs_a = (u16*)alloc(HH / 2);
    u16* wt_r1_a = (u16*)alloc(HH / 2);
    u16* wt_l0_b = (u16*)alloc(HH / 2);
    u16* wt_l1_b = (u16*)alloc(HH / 2);
    u16* wt_l2_b = (u16*)alloc(HH / 2);
    u16* wt_rs_b = (u16*)alloc(HH / 2);
    u16* wt_r1_b = (u16*)alloc(HH / 2);
    u16* wt_atts = (u16*)alloc(HH / 2);
    u16* wt_attc = (u16*)alloc(HH / 2);
    u16* wt_w1   = (u16*)alloc((size_t)256 * 1024 / 2);
    // CSR
    int*   cnt_ss = (int*)alloc(Ns);
    int*   cnt_sn = (int*)alloc(Ne);
    int*   cnt_ns = (int*)alloc(Ns);
    float* inv_ss = alloc(Ns);
    float* inv_sn = alloc(Ne);
    float* inv_ns = alloc(Ns);
    int*   rp_ss  = (int*)alloc(Ns + 1);
    int*   rp_sn  = (int*)alloc(Ne + 1);
    int*   rp_ns  = (int*)alloc(Ns + 1);
    int*   col_ss = (int*)alloc(Ess);
    int*   col_sn = (int*)alloc(Esn);
    int*   col_ns = (int*)alloc(Ens);
    int*   fillc  = (int*)alloc(Nmax);
    int*   bsums  = (int*)alloc(nb_max);
    // attention / head
    float* scores = alloc(Ns);
    int*   rp_b   = (int*)alloc(B + 1);
    float* g      = alloc((size_t)B * H);
    float* z      = alloc((size_t)B * 4 * H);
    float* hbuf   = alloc((size_t)B * H);
    (void)ws_size; (void)n_in; (void)out_size;

    auto gemm = [&](const float* A, const u16* Wt, const float* bias,
                    float* C, int M, int K, int flags) {
        int nbm = (M + GTM - 1) / GTM;
        gemm_mfma<<<dim3((unsigned)(nbm * 2)), dim3(256), 0, stream>>>(A, Wt, bias, C, M, K, flags);
    };
    auto pack = [&](const float* W, const float* Wadd, u16* o, int Kpart) {
        pack_wt<<<(256 * Kpart + 255) / 256, 256, 0, stream>>>(W, Wadd, o, Kpart, Kpart, 0);
    };

    // ---- weight packing ----
    pack(W_ps, nullptr, wt_ps, 768);
    pack(W_pn, nullptr, wt_pn, 768);
    pack(W_pc, nullptr, wt_pc, 768);
    u16* wt_l0[2] = {wt_l0_a, wt_l0_b};
    u16* wt_l1[2] = {wt_l1_a, wt_l1_b};
    u16* wt_l2[2] = {wt_l2_a, wt_l2_b};
    u16* wt_rs[2] = {wt_rs_a, wt_rs_b};
    u16* wt_r1[2] = {wt_r1_a, wt_r1_b};
    float* bsum[2] = {bsum0, bsum1};
    for (int l = 0; l < L; ++l) {
        const float* Wl = conv_Wl + (size_t)l * 3 * HH;
        const float* bl = conv_bl + (size_t)l * 3 * H;
        const float* Wr = conv_Wr + (size_t)l * 3 * HH;
        pack(Wl,          nullptr,     wt_l0[l], 256);   // Wl_ss
        pack(Wl + HH,     nullptr,     wt_l1[l], 256);   // Wl_sn
        pack(Wl + 2 * HH, nullptr,     wt_l2[l], 256);   // Wl_ns
        pack(Wr,          Wr + 2 * HH, wt_rs[l], 256);   // Wr_ss + Wr_ns
        pack(Wr + HH,     nullptr,     wt_r1[l], 256);   // Wr_sn
        vsum_bias<<<1, 256, 0, stream>>>(bl, bl + 2 * H, bsum[l], H);
    }
    pack(W_atts, nullptr, wt_atts, 256);
    pack(W_attc, nullptr, wt_attc, 256);
    pack(W1,     nullptr, wt_w1, 1024);

    // ---- degree counts + CSR ----
    hipMemsetAsync(cnt_ss, 0, (size_t)Ns * 4, stream);
    hipMemsetAsync(cnt_sn, 0, (size_t)Ne * 4, stream);
    hipMemsetAsync(cnt_ns, 0, (size_t)Ns * 4, stream);
    count_edges<<<(Ess + 255) / 256, 256, 0, stream>>>(dst_ss, Ess, cnt_ss);
    count_edges<<<(Esn + 255) / 256, 256, 0, stream>>>(dst_sn, Esn, cnt_sn);
    count_edges<<<(Ens + 255) / 256, 256, 0, stream>>>(dst_ns, Ens, cnt_ns);
    make_inv<<<(Ns + 255) / 256, 256, 0, stream>>>(cnt_ss, inv_ss, Ns);
    make_inv<<<(Ne + 255) / 256, 256, 0, stream>>>(cnt_sn, inv_sn, Ne);
    make_inv<<<(Ns + 255) / 256, 256, 0, stream>>>(cnt_ns, inv_ns, Ns);
    auto build_csr = [&](const int* src, const int* dst, int E, int Nd,
                         const int* cnt, int* rowptr, int* colidx) {
        int nb = (Nd + 255) / 256;
        scan1<<<nb, 256, 0, stream>>>(cnt, Nd, rowptr, bsums);
        scan2<<<1, 256, 0, stream>>>(bsums, nb);
        scan3<<<nb, 256, 0, stream>>>(rowptr, bsums, Nd);
        hipMemsetAsync(fillc, 0, (size_t)Nd * 4, stream);
        csr_fill<<<(E + 255) / 256, 256, 0, stream>>>(src, dst, E, rowptr, fillc, colidx);
    };
    build_csr(src_ss, dst_ss, Ess, Ns, cnt_ss, rp_ss, col_ss);
    build_csr(src_sn, dst_sn, Esn, Ne, cnt_sn, rp_sn, col_sn);
    build_csr(src_ns, dst_ns, Ens, Ns, cnt_ns, rp_ns, col_ns);

    // batch segment bounds (batch_s sorted)
    batch_bounds<<<(Ns + 1 + 255) / 256, 256, 0, stream>>>(batch_s, Ns, B, rp_b);

    // ---- input projections ----
    gemm(x_s,   wt_ps, b_ps, xs_a, Ns, 768, F_RELU);
    gemm(x_n,   wt_pn, b_pn, xn_a, Ne, 768, F_RELU);
    gemm(claim, wt_pc, b_pc, ch,   B,  768, F_RELU);

    // ---- GNN layers ----
    float* xs_cur = xs_a; float* xs_nxt = xs_b;
    float* xn_cur = xn_a; float* xn_nxt = xn_b;
    for (int l = 0; l < L; ++l) {
        const float* bl = conv_bl + (size_t)l * 3 * H;

        gather_mean<<<(unsigned)(((long long)Ns * 64 + 255) / 256), 256, 0, stream>>>(
            xs_cur, rp_ss, col_ss, inv_ss, m_big, Ns);
        gemm(m_big, wt_l0[l], bsum[l], xs_nxt, Ns, 256, 0);

        gather_mean<<<(unsigned)(((long long)Ns * 64 + 255) / 256), 256, 0, stream>>>(
            xn_cur, rp_ns, col_ns, inv_ns, m_big, Ns);
        gemm(m_big, wt_l2[l], nullptr, xs_nxt, Ns, 256, F_ACC);

        gemm(xs_cur, wt_rs[l], nullptr, xs_nxt, Ns, 256, F_ACC | F_RELU);

        gather_mean<<<(unsigned)(((long long)Ne * 64 + 255) / 256), 256, 0, stream>>>(
            xs_cur, rp_sn, col_sn, inv_sn, m_big, Ne);
        gemm(m_big, wt_l1[l], bl + H, xn_nxt, Ne, 256, 0);
        gemm(xn_cur, wt_r1[l], nullptr, xn_nxt, Ne, 256, F_ACC | F_RELU);

        float* t;
        t = xs_cur; xs_cur = xs_nxt; xs_nxt = t;
        t = xn_cur; xn_cur = xn_nxt; xn_nxt = t;
    }

    // ---- attentive pooling (segmented, no atomics) ----
    gemm(ch,     wt_attc, nullptr, c_att, B,  256, 0);
    gemm(xs_cur, wt_atts, nullptr, m_big, Ns, 256, 0);   // s_att in m_big
    scores_kernel<<<(unsigned)(((long long)Ns * 64 + 255) / 256), 256, 0, stream>>>(
        m_big, c_att, batch_s, scores, Ns);
    pool_kernel<<<B, 256, 0, stream>>>(scores, xs_cur, rp_b, g);

    // ---- head MLP ----
    z_kernel<<<(B * H + 255) / 256, 256, 0, stream>>>(ch, g, z, B, H);
    gemm(z, wt_w1, b1, hbuf, B, 1024, F_RELU);
    out_kernel<<<(B * 2 + 255) / 256, 256, 0, stream>>>(hbuf, W2, b2, (float*)d_out, B, 256);
}

// Round 4
// 1649.921 us; speedup vs baseline: 1.2392x; 1.2392x over previous
//
#include <hip/hip_runtime.h>
#include <hip/hip_bf16.h>
#include <cstddef>

#define F_ACC  1
#define F_RELU 2
#define F_OUTB 4   // also write bf16 mirror Cb
#define F_NOC  8   // skip fp32 C write (C may still be read for F_ACC)

typedef unsigned short u16;
typedef short bf16x8 __attribute__((ext_vector_type(8)));
typedef float f32x4 __attribute__((ext_vector_type(4)));

__device__ inline u16 f2b(float x) {
    union { float f; unsigned u; } c; c.f = x;
    unsigned r = c.u + 0x7FFF + ((c.u >> 16) & 1);
    return (u16)(r >> 16);
}
__device__ inline float b2f(u16 x) {
    union { unsigned u; float f; } c; c.u = ((unsigned)x) << 16;
    return c.f;
}

typedef __attribute__((address_space(3))) unsigned int lds_u32;
typedef __attribute__((address_space(1))) unsigned int glb_u32;
// async global->LDS, 16B per lane; LDS dest = uniform base + lane*16
__device__ inline void glds16(const u16* g, u16* l) {
    __builtin_amdgcn_global_load_lds((const glb_u32*)g, (lds_u32*)l, 16, 0, 0);
}

#define GTM 128
#define GTN 128
#define GBK 64
#define LDA 72   // a32 LDS pad (u16): breaks ds_write bank conflicts

// ---------------- GEMM variant 1: fp32 A (cvt staging, round-0 proven path) ----------
__global__ __launch_bounds__(256) void gemm_a32(
    const float* __restrict__ A, const u16* __restrict__ Wt,
    const float* __restrict__ bias, float* __restrict__ C, u16* __restrict__ Cb,
    int M, int K, int flags)
{
    __shared__ u16 As[GTM][LDA];
    __shared__ u16 Bs[GTN][LDA];
    const int tid  = threadIdx.x;
    const int bm   = blockIdx.x * GTM;
    const int bn   = blockIdx.y * GTN;
    const int wave = tid >> 6, lane = tid & 63;
    const int wm   = (wave >> 1) * 64, wn = (wave & 1) * 64;
    const int l16  = lane & 15, lq = lane >> 4;
    const int sr   = tid >> 1;          // 0..127
    const int sk   = (tid & 1) * 32;    // 0 or 32

    f32x4 acc[4][4] = {};

    const int  arow = bm + sr;
    const bool aok  = arow < M;
    const float* Ap = A + (size_t)(aok ? arow : 0) * K + sk;
    const u16*   Wp = Wt + (size_t)(bn + sr) * K + sk;

    for (int k0 = 0; k0 < K; k0 += GBK) {
#pragma unroll
        for (int i = 0; i < 4; ++i) {
            float4 a, b;
            if (aok) {
                a = *(const float4*)(Ap + k0 + i * 8);
                b = *(const float4*)(Ap + k0 + i * 8 + 4);
            } else {
                a = make_float4(0.f, 0.f, 0.f, 0.f);
                b = a;
            }
            ushort4 lo, hi;
            lo.x = f2b(a.x); lo.y = f2b(a.y); lo.z = f2b(a.z); lo.w = f2b(a.w);
            hi.x = f2b(b.x); hi.y = f2b(b.y); hi.z = f2b(b.z); hi.w = f2b(b.w);
            *(ushort4*)&As[sr][sk + i * 8]     = lo;
            *(ushort4*)&As[sr][sk + i * 8 + 4] = hi;
        }
#pragma unroll
        for (int i = 0; i < 4; ++i)
            *(float4*)&Bs[sr][sk + i * 8] = *(const float4*)(Wp + k0 + i * 8);
        __syncthreads();
#pragma unroll
        for (int kk = 0; kk < GBK; kk += 32) {
            bf16x8 af[4], bfr[4];
#pragma unroll
            for (int mt = 0; mt < 4; ++mt)
                af[mt] = *(const bf16x8*)&As[wm + mt * 16 + l16][kk + lq * 8];
#pragma unroll
            for (int nt = 0; nt < 4; ++nt)
                bfr[nt] = *(const bf16x8*)&Bs[wn + nt * 16 + l16][kk + lq * 8];
#pragma unroll
            for (int mt = 0; mt < 4; ++mt)
#pragma unroll
                for (int nt = 0; nt < 4; ++nt)
                    acc[mt][nt] = __builtin_amdgcn_mfma_f32_16x16x32_bf16(
                        af[mt], bfr[nt], acc[mt][nt], 0, 0, 0);
        }
        __syncthreads();
    }

    // epilogue: C/D layout col=lane&15, row=(lane>>4)*4+reg
#pragma unroll
    for (int mt = 0; mt < 4; ++mt) {
#pragma unroll
        for (int nt = 0; nt < 4; ++nt) {
            int col = bn + wn + nt * 16 + l16;
            float bv = (bias != nullptr) ? bias[col] : 0.f;
#pragma unroll
            for (int r = 0; r < 4; ++r) {
                int row = bm + wm + mt * 16 + lq * 4 + r;
                if (row >= M) continue;
                float v = acc[mt][nt][r] + bv;
                size_t o = (size_t)row * 256 + col;
                if (flags & F_ACC) v += C[o];
                if (flags & F_RELU) v = fmaxf(v, 0.f);
                if (!(flags & F_NOC)) C[o] = v;
                if (flags & F_OUTB) Cb[o] = f2b(v);
            }
        }
    }
}

// ---------------- GEMM variant 2: bf16 A via global_load_lds (m97 structure) --------
__global__ __launch_bounds__(256) void gemm_a16(
    const u16* __restrict__ A, const u16* __restrict__ Wt,
    const float* __restrict__ bias, float* __restrict__ C, u16* __restrict__ Cb,
    int M, int K, int flags)
{
    __shared__ u16 As[GTM][64];   // linear: required by global_load_lds dest layout
    __shared__ u16 Bs[GTN][64];
    const int tid  = threadIdx.x;
    const int bm   = blockIdx.x * GTM;
    const int bn   = blockIdx.y * GTN;
    const int wave = tid >> 6, lane = tid & 63;
    const int wm   = (wave >> 1) * 64, wn = (wave & 1) * 64;
    const int l16  = lane & 15, lq = lane >> 4;
    const int lrow = lane >> 3;        // 0..7 row within 8-row group
    const int lcol = (lane & 7) * 8;   // u16 col within 64

    f32x4 acc[4][4] = {};

    for (int k0 = 0; k0 < K; k0 += GBK) {
        // wave w stages As rows w*32..w*32+31 and Bs rows w*32..w*32+31
#pragma unroll
        for (int j = 0; j < 4; ++j) {
            int r  = wave * 32 + j * 8 + lrow;
            int ar = bm + r; if (ar >= M) ar = M - 1;   // clamp: no fault, garbage rows unused
            glds16(A  + (size_t)ar       * K + k0 + lcol, &As[wave * 32 + j * 8][0]);
            glds16(Wt + (size_t)(bn + r) * K + k0 + lcol, &Bs[wave * 32 + j * 8][0]);
        }
        __syncthreads();
#pragma unroll
        for (int kk = 0; kk < GBK; kk += 32) {
            bf16x8 af[4], bfr[4];
#pragma unroll
            for (int mt = 0; mt < 4; ++mt)
                af[mt] = *(const bf16x8*)&As[wm + mt * 16 + l16][kk + lq * 8];
#pragma unroll
            for (int nt = 0; nt < 4; ++nt)
                bfr[nt] = *(const bf16x8*)&Bs[wn + nt * 16 + l16][kk + lq * 8];
#pragma unroll
            for (int mt = 0; mt < 4; ++mt)
#pragma unroll
                for (int nt = 0; nt < 4; ++nt)
                    acc[mt][nt] = __builtin_amdgcn_mfma_f32_16x16x32_bf16(
                        af[mt], bfr[nt], acc[mt][nt], 0, 0, 0);
        }
        __syncthreads();
    }

#pragma unroll
    for (int mt = 0; mt < 4; ++mt) {
#pragma unroll
        for (int nt = 0; nt < 4; ++nt) {
            int col = bn + wn + nt * 16 + l16;
            float bv = (bias != nullptr) ? bias[col] : 0.f;
#pragma unroll
            for (int r = 0; r < 4; ++r) {
                int row = bm + wm + mt * 16 + lq * 4 + r;
                if (row >= M) continue;
                float v = acc[mt][nt][r] + bv;
                size_t o = (size_t)row * 256 + col;
                if (flags & F_ACC) v += C[o];
                if (flags & F_RELU) v = fmaxf(v, 0.f);
                if (!(flags & F_NOC)) C[o] = v;
                if (flags & F_OUTB) Cb[o] = f2b(v);
            }
        }
    }
}

// W [Kpart,256] fp32 (+optional addend) -> out[n][koff+k] bf16, out is [256][Ktot]
__global__ void pack_wt(const float* __restrict__ W, const float* __restrict__ Wadd,
                        u16* __restrict__ out, int Kpart, int Ktot, int koff)
{
    int idx = blockIdx.x * blockDim.x + threadIdx.x;
    if (idx >= 256 * Kpart) return;
    int n = idx / Kpart, k = idx % Kpart;
    float v = W[(size_t)k * 256 + n];
    if (Wadd) v += Wadd[(size_t)k * 256 + n];
    out[(size_t)n * Ktot + koff + k] = f2b(v);
}

__global__ void vsum_bias(const float* __restrict__ a, const float* __restrict__ b,
                          float* __restrict__ o, int n)
{
    int i = blockIdx.x * blockDim.x + threadIdx.x;
    if (i < n) o[i] = a[i] + b[i];
}

// ---------------- CSR construction ----------------

__global__ void count_edges(const int* __restrict__ dst, int E, int* __restrict__ cnt)
{
    int i = blockIdx.x * blockDim.x + threadIdx.x;
    if (i < E) atomicAdd(&cnt[dst[i]], 1);
}

__global__ void make_inv(const int* __restrict__ cnt, float* __restrict__ inv, int n)
{
    int i = blockIdx.x * blockDim.x + threadIdx.x;
    if (i < n) {
        int c = cnt[i];
        inv[i] = 1.0f / (float)(c > 1 ? c : 1);
    }
}

__global__ void scan1(const int* __restrict__ cnt, int n, int* __restrict__ rowptr,
                      int* __restrict__ bsums)
{
    __shared__ int tmp[256];
    int i = blockIdx.x * 256 + threadIdx.x;
    tmp[threadIdx.x] = (i < n) ? cnt[i] : 0;
    __syncthreads();
    for (int off = 1; off < 256; off <<= 1) {
        int t = (threadIdx.x >= (unsigned)off) ? tmp[threadIdx.x - off] : 0;
        __syncthreads();
        tmp[threadIdx.x] += t;
        __syncthreads();
    }
    if (i < n) rowptr[i + 1] = tmp[threadIdx.x];
    if (threadIdx.x == 255) bsums[blockIdx.x] = tmp[255];
}

__global__ void scan2(int* __restrict__ bsums, int nb)
{
    __shared__ int tmp[256];
    __shared__ int carry;
    if (threadIdx.x == 0) carry = 0;
    __syncthreads();
    for (int base = 0; base < nb; base += 256) {
        int i = base + threadIdx.x;
        tmp[threadIdx.x] = (i < nb) ? bsums[i] : 0;
        __syncthreads();
        for (int off = 1; off < 256; off <<= 1) {
            int t = (threadIdx.x >= (unsigned)off) ? tmp[threadIdx.x - off] : 0;
            __syncthreads();
            tmp[threadIdx.x] += t;
            __syncthreads();
        }
        int c = carry;
        if (i < nb) bsums[i] = tmp[threadIdx.x] + c;
        __syncthreads();
        if (threadIdx.x == 255) carry = c + tmp[255];
        __syncthreads();
    }
}

__global__ void scan3(int* __restrict__ rowptr, const int* __restrict__ bsums, int n)
{
    int i = blockIdx.x * 256 + threadIdx.x;
    if (i == 0) rowptr[0] = 0;
    if (i < n && blockIdx.x > 0) rowptr[i + 1] += bsums[blockIdx.x - 1];
}

__global__ void csr_fill(const int* __restrict__ src, const int* __restrict__ dst, int E,
                         const int* __restrict__ rowptr, int* __restrict__ fillc,
                         int* __restrict__ col)
{
    int e = blockIdx.x * blockDim.x + threadIdx.x;
    if (e < E) {
        int d = dst[e];
        int p = atomicAdd(&fillc[d], 1);
        col[rowptr[d] + p] = src[e];
    }
}

// ---------------- CSR mean-aggregation: bf16 in, fp32 accum, bf16 out ----------------
__global__ __launch_bounds__(256) void gather_mean_b16(
    const u16* __restrict__ X, const int* __restrict__ rowptr,
    const int* __restrict__ col, const float* __restrict__ inv,
    u16* __restrict__ out, int Nd)
{
    long long gid = (long long)blockIdx.x * blockDim.x + threadIdx.x;
    int row = (int)(gid >> 6);
    if (row >= Nd) return;
    int c4 = (threadIdx.x & 63) << 2;   // 4 bf16 per lane (8B)
    int e0 = rowptr[row], e1 = rowptr[row + 1];
    float a0 = 0.f, a1 = 0.f, a2 = 0.f, a3 = 0.f;
    int e = e0;
    for (; e + 1 < e1; e += 2) {
        int s0 = col[e], s1 = col[e + 1];
        ushort4 v0 = *(const ushort4*)(X + (size_t)s0 * 256 + c4);
        ushort4 v1 = *(const ushort4*)(X + (size_t)s1 * 256 + c4);
        a0 += b2f(v0.x) + b2f(v1.x); a1 += b2f(v0.y) + b2f(v1.y);
        a2 += b2f(v0.z) + b2f(v1.z); a3 += b2f(v0.w) + b2f(v1.w);
    }
    if (e < e1) {
        int s = col[e];
        ushort4 v = *(const ushort4*)(X + (size_t)s * 256 + c4);
        a0 += b2f(v.x); a1 += b2f(v.y); a2 += b2f(v.z); a3 += b2f(v.w);
    }
    float sc = inv[row];
    ushort4 o;
    o.x = f2b(a0 * sc); o.y = f2b(a1 * sc); o.z = f2b(a2 * sc); o.w = f2b(a3 * sc);
    *(ushort4*)(out + (size_t)row * 256 + c4) = o;
}

// ---------------- attention / pooling (segmented, no atomics) ----------------

// scores[i] = dot(s_att[i,:], c_att[batch[i],:]) -- one wave per row (fp32 inputs)
__global__ __launch_bounds__(256) void scores_kernel(
    const float* __restrict__ s_att, const float* __restrict__ c_att,
    const int* __restrict__ batch, float* __restrict__ scores, int Ns)
{
    long long gid = (long long)blockIdx.x * blockDim.x + threadIdx.x;
    int row = (int)(gid >> 6);
    if (row >= Ns) return;
    int lane = threadIdx.x & 63;
    int b = batch[row];
    float4 s4 = *(const float4*)(s_att + (size_t)row * 256 + (lane << 2));
    float4 c4 = *(const float4*)(c_att + (size_t)b * 256 + (lane << 2));
    float p = s4.x * c4.x + s4.y * c4.y + s4.z * c4.z + s4.w * c4.w;
#pragma unroll
    for (int off = 32; off > 0; off >>= 1) p += __shfl_down(p, off, 64);
    if (lane == 0) scores[row] = p;
}

// batch_s is sorted: rp[b] = first row with batch >= b; rp[B] = Ns
__global__ void batch_bounds(const int* __restrict__ batch, int Ns, int B,
                             int* __restrict__ rp)
{
    int i = blockIdx.x * blockDim.x + threadIdx.x;
    if (i > Ns) return;
    if (i == 0) {
        int b1 = batch[0];
        for (int b = 0; b <= b1; ++b) rp[b] = 0;
    } else if (i == Ns) {
        int b0 = batch[Ns - 1];
        for (int b = b0 + 1; b <= B; ++b) rp[b] = Ns;
    } else {
        int b0 = batch[i - 1], b1 = batch[i];
        for (int b = b0 + 1; b <= b1; ++b) rp[b] = i;
    }
}

// one block per graph: softmax over contiguous rows + weighted column sum (xs bf16)
__global__ __launch_bounds__(256) void pool_kernel(
    float* __restrict__ scores, const u16* __restrict__ xs,
    const int* __restrict__ rp, float* __restrict__ g)
{
    __shared__ float red[256];
    const int b = blockIdx.x, tid = threadIdx.x;
    const int r0 = rp[b], r1 = rp[b + 1];
    if (r0 >= r1) { g[(size_t)b * 256 + tid] = 0.f; return; }
    float m = -3.4e38f;
    for (int r = r0 + tid; r < r1; r += 256) m = fmaxf(m, scores[r]);
    red[tid] = m; __syncthreads();
    for (int s = 128; s > 0; s >>= 1) {
        if (tid < s) red[tid] = fmaxf(red[tid], red[tid + s]);
        __syncthreads();
    }
    m = red[0]; __syncthreads();
    float sum = 0.f;
    for (int r = r0 + tid; r < r1; r += 256) {
        float e = __expf(scores[r] - m);
        scores[r] = e;
        sum += e;
    }
    red[tid] = sum; __syncthreads();
    for (int s = 128; s > 0; s >>= 1) {
        if (tid < s) red[tid] += red[tid + s];
        __syncthreads();
    }
    const float inv = 1.0f / red[0];
    __syncthreads();
    float acc = 0.f;
    for (int r = r0; r < r1; ++r)
        acc += scores[r] * b2f(xs[(size_t)r * 256 + tid]);
    g[(size_t)b * 256 + tid] = acc * inv;
}

__global__ void z_kernel(const float* __restrict__ ch, const float* __restrict__ g,
                         float* __restrict__ z, int B, int H)
{
    int i = blockIdx.x * blockDim.x + threadIdx.x;
    if (i >= B * H) return;
    int b = i / H, c = i % H;
    float cv = ch[i], gv = g[i];
    float* zr = z + (size_t)b * 4 * H;
    zr[c]         = cv;
    zr[H + c]     = gv;
    zr[2 * H + c] = fabsf(cv - gv);
    zr[3 * H + c] = cv * gv;
}

__global__ void out_kernel(const float* __restrict__ h, const float* __restrict__ W2,
                           const float* __restrict__ b2, float* __restrict__ out, int B, int H)
{
    int i = blockIdx.x * blockDim.x + threadIdx.x;
    if (i >= B * 2) return;
    int b = i >> 1, j = i & 1;
    float s = b2[j];
    const float* hr = h + (size_t)b * H;
    for (int k = 0; k < H; ++k) s += hr[k] * W2[k * 2 + j];
    out[i] = s;
}

extern "C" void kernel_launch(void* const* d_in, const int* in_sizes, int n_in,
                              void* d_out, int out_size, void* d_ws, size_t ws_size,
                              hipStream_t stream)
{
    const float* x_s    = (const float*)d_in[0];
    const float* x_n    = (const float*)d_in[1];
    const float* claim  = (const float*)d_in[2];
    const int*   batch_s= (const int*)d_in[3];
    const int*   src_ss = (const int*)d_in[4];
    const int*   dst_ss = (const int*)d_in[5];
    const int*   src_sn = (const int*)d_in[6];
    const int*   dst_sn = (const int*)d_in[7];
    const int*   src_ns = (const int*)d_in[8];
    const int*   dst_ns = (const int*)d_in[9];
    const float* W_ps   = (const float*)d_in[10];
    const float* b_ps   = (const float*)d_in[11];
    const float* W_pn   = (const float*)d_in[12];
    const float* b_pn   = (const float*)d_in[13];
    const float* W_pc   = (const float*)d_in[14];
    const float* b_pc   = (const float*)d_in[15];
    const float* conv_Wl= (const float*)d_in[16];
    const float* conv_bl= (const float*)d_in[17];
    const float* conv_Wr= (const float*)d_in[18];
    const float* W_attc = (const float*)d_in[19];
    const float* W_atts = (const float*)d_in[20];
    const float* W1     = (const float*)d_in[21];
    const float* b1     = (const float*)d_in[22];
    const float* W2     = (const float*)d_in[23];
    const float* b2     = (const float*)d_in[24];

    const int in_dim = 768, H = 256;
    const int Ns  = in_sizes[0] / in_dim;
    const int Ne  = in_sizes[1] / in_dim;
    const int B   = in_sizes[2] / in_dim;
    const int Ess = in_sizes[4];
    const int Esn = in_sizes[6];
    const int Ens = in_sizes[8];
    const int L   = in_sizes[16] / (3 * H * H);
    const int Nmax = (Ns > Ne) ? Ns : Ne;
    const int nb_max = (Nmax + 255) / 256;
    const size_t HH = (size_t)H * H;

    float* ws = (float*)d_ws;
    size_t off = 0;
    auto alloc = [&](size_t n) { float* p = ws + off; off += (n + 63) & ~(size_t)63; return p; };
    // bf16 activations (u16 [N][256]); sizes in float-slots = elems/2
    u16* xs_a  = (u16*)alloc((size_t)Ns * 128);
    u16* xs_b  = (u16*)alloc((size_t)Ns * 128);
    u16* xn_a  = (u16*)alloc((size_t)Ne * 128);
    u16* xn_b  = (u16*)alloc((size_t)Ne * 128);
    u16* m_big = (u16*)alloc((size_t)Nmax * 128);   // gather output (bf16)
    u16* ch_b  = (u16*)alloc((size_t)B * 128);      // bf16 mirror of ch
    float* Cs    = alloc((size_t)Nmax * H);          // fp32 GEMM accum scratch / s_att
    float* ch    = alloc((size_t)B * H);
    float* c_att = alloc((size_t)B * H);
    float* bsum0 = alloc(H);
    float* bsum1 = alloc(H);
    // packed bf16 weights (u16, [256][K] n-major)
    u16* wt_ps   = (u16*)alloc((size_t)256 * 768 / 2);
    u16* wt_pn   = (u16*)alloc((size_t)256 * 768 / 2);
    u16* wt_pc   = (u16*)alloc((size_t)256 * 768 / 2);
    u16* wt_l0_a = (u16*)alloc(HH / 2);
    u16* wt_l1_a = (u16*)alloc(HH / 2);
    u16* wt_l2_a = (u16*)alloc(HH / 2);
    u16* wt_rs_a = (u16*)alloc(HH / 2);
    u16* wt_r1_a = (u16*)alloc(HH / 2);
    u16* wt_l0_b = (u16*)alloc(HH / 2);
    u16* wt_l1_b = (u16*)alloc(HH / 2);
    u16* wt_l2_b = (u16*)alloc(HH / 2);
    u16* wt_rs_b = (u16*)alloc(HH / 2);
    u16* wt_r1_b = (u16*)alloc(HH / 2);
    u16* wt_atts = (u16*)alloc(HH / 2);
    u16* wt_attc = (u16*)alloc(HH / 2);
    u16* wt_w1   = (u16*)alloc((size_t)256 * 1024 / 2);
    // CSR
    int*   cnt_ss = (int*)alloc(Ns);
    int*   cnt_sn = (int*)alloc(Ne);
    int*   cnt_ns = (int*)alloc(Ns);
    float* inv_ss = alloc(Ns);
    float* inv_sn = alloc(Ne);
    float* inv_ns = alloc(Ns);
    int*   rp_ss  = (int*)alloc(Ns + 1);
    int*   rp_sn  = (int*)alloc(Ne + 1);
    int*   rp_ns  = (int*)alloc(Ns + 1);
    int*   col_ss = (int*)alloc(Ess);
    int*   col_sn = (int*)alloc(Esn);
    int*   col_ns = (int*)alloc(Ens);
    int*   fillc  = (int*)alloc(Nmax);
    int*   bsums  = (int*)alloc(nb_max);
    // attention / head
    float* scores = alloc(Ns);
    int*   rp_b   = (int*)alloc(B + 1);
    float* g      = alloc((size_t)B * H);
    float* z      = alloc((size_t)B * 4 * H);
    float* hbuf   = alloc((size_t)B * H);
    (void)ws_size; (void)n_in; (void)out_size;

    auto gemm32 = [&](const float* A, const u16* Wt, const float* bias,
                      float* C, u16* Cb, int M, int K, int flags) {
        dim3 grid((M + GTM - 1) / GTM, 2);
        gemm_a32<<<grid, dim3(256), 0, stream>>>(A, Wt, bias, C, Cb, M, K, flags);
    };
    auto gemm16 = [&](const u16* A, const u16* Wt, const float* bias,
                      float* C, u16* Cb, int M, int K, int flags) {
        dim3 grid((M + GTM - 1) / GTM, 2);
        gemm_a16<<<grid, dim3(256), 0, stream>>>(A, Wt, bias, C, Cb, M, K, flags);
    };
    auto pack = [&](const float* W, const float* Wadd, u16* o, int Kpart) {
        pack_wt<<<(256 * Kpart + 255) / 256, 256, 0, stream>>>(W, Wadd, o, Kpart, Kpart, 0);
    };

    // ---- weight packing ----
    pack(W_ps, nullptr, wt_ps, 768);
    pack(W_pn, nullptr, wt_pn, 768);
    pack(W_pc, nullptr, wt_pc, 768);
    u16* wt_l0[2] = {wt_l0_a, wt_l0_b};
    u16* wt_l1[2] = {wt_l1_a, wt_l1_b};
    u16* wt_l2[2] = {wt_l2_a, wt_l2_b};
    u16* wt_rs[2] = {wt_rs_a, wt_rs_b};
    u16* wt_r1[2] = {wt_r1_a, wt_r1_b};
    float* bsum[2] = {bsum0, bsum1};
    for (int l = 0; l < L; ++l) {
        const float* Wl = conv_Wl + (size_t)l * 3 * HH;
        const float* bl = conv_bl + (size_t)l * 3 * H;
        const float* Wr = conv_Wr + (size_t)l * 3 * HH;
        pack(Wl,          nullptr,     wt_l0[l], 256);   // Wl_ss
        pack(Wl + HH,     nullptr,     wt_l1[l], 256);   // Wl_sn
        pack(Wl + 2 * HH, nullptr,     wt_l2[l], 256);   // Wl_ns
        pack(Wr,          Wr + 2 * HH, wt_rs[l], 256);   // Wr_ss + Wr_ns
        pack(Wr + HH,     nullptr,     wt_r1[l], 256);   // Wr_sn
        vsum_bias<<<1, 256, 0, stream>>>(bl, bl + 2 * H, bsum[l], H);
    }
    pack(W_atts, nullptr, wt_atts, 256);
    pack(W_attc, nullptr, wt_attc, 256);
    pack(W1,     nullptr, wt_w1, 1024);

    // ---- degree counts + CSR ----
    hipMemsetAsync(cnt_ss, 0, (size_t)Ns * 4, stream);
    hipMemsetAsync(cnt_sn, 0, (size_t)Ne * 4, stream);
    hipMemsetAsync(cnt_ns, 0, (size_t)Ns * 4, stream);
    count_edges<<<(Ess + 255) / 256, 256, 0, stream>>>(dst_ss, Ess, cnt_ss);
    count_edges<<<(Esn + 255) / 256, 256, 0, stream>>>(dst_sn, Esn, cnt_sn);
    count_edges<<<(Ens + 255) / 256, 256, 0, stream>>>(dst_ns, Ens, cnt_ns);
    make_inv<<<(Ns + 255) / 256, 256, 0, stream>>>(cnt_ss, inv_ss, Ns);
    make_inv<<<(Ne + 255) / 256, 256, 0, stream>>>(cnt_sn, inv_sn, Ne);
    make_inv<<<(Ns + 255) / 256, 256, 0, stream>>>(cnt_ns, inv_ns, Ns);
    auto build_csr = [&](const int* src, const int* dst, int E, int Nd,
                         const int* cnt, int* rowptr, int* colidx) {
        int nb = (Nd + 255) / 256;
        scan1<<<nb, 256, 0, stream>>>(cnt, Nd, rowptr, bsums);
        scan2<<<1, 256, 0, stream>>>(bsums, nb);
        scan3<<<nb, 256, 0, stream>>>(rowptr, bsums, Nd);
        hipMemsetAsync(fillc, 0, (size_t)Nd * 4, stream);
        csr_fill<<<(E + 255) / 256, 256, 0, stream>>>(src, dst, E, rowptr, fillc, colidx);
    };
    build_csr(src_ss, dst_ss, Ess, Ns, cnt_ss, rp_ss, col_ss);
    build_csr(src_sn, dst_sn, Esn, Ne, cnt_sn, rp_sn, col_sn);
    build_csr(src_ns, dst_ns, Ens, Ns, cnt_ns, rp_ns, col_ns);

    // batch segment bounds (batch_s sorted)
    batch_bounds<<<(Ns + 1 + 255) / 256, 256, 0, stream>>>(batch_s, Ns, B, rp_b);

    // ---- input projections (fp32 A path; bf16 mirrors become the activations) ----
    gemm32(x_s,   wt_ps, b_ps, Cs, xs_a, Ns, 768, F_RELU | F_OUTB | F_NOC);
    gemm32(x_n,   wt_pn, b_pn, Cs, xn_a, Ne, 768, F_RELU | F_OUTB | F_NOC);
    gemm32(claim, wt_pc, b_pc, ch, ch_b, B,  768, F_RELU | F_OUTB);

    // ---- GNN layers (bf16 activations, fp32 accumulation in Cs) ----
    u16* xs_cur = xs_a; u16* xs_nxt = xs_b;
    u16* xn_cur = xn_a; u16* xn_nxt = xn_b;
    for (int l = 0; l < L; ++l) {
        const float* bl = conv_bl + (size_t)l * 3 * H;

        gather_mean_b16<<<(unsigned)(((long long)Ns * 64 + 255) / 256), 256, 0, stream>>>(
            xs_cur, rp_ss, col_ss, inv_ss, m_big, Ns);
        gemm16(m_big, wt_l0[l], bsum[l], Cs, nullptr, Ns, 256, 0);

        gather_mean_b16<<<(unsigned)(((long long)Ns * 64 + 255) / 256), 256, 0, stream>>>(
            xn_cur, rp_ns, col_ns, inv_ns, m_big, Ns);
        gemm16(m_big, wt_l2[l], nullptr, Cs, nullptr, Ns, 256, F_ACC);

        gemm16(xs_cur, wt_rs[l], nullptr, Cs, xs_nxt, Ns, 256,
               F_ACC | F_RELU | F_OUTB | F_NOC);

        gather_mean_b16<<<(unsigned)(((long long)Ne * 64 + 255) / 256), 256, 0, stream>>>(
            xs_cur, rp_sn, col_sn, inv_sn, m_big, Ne);
        gemm16(m_big, wt_l1[l], bl + H, Cs, nullptr, Ne, 256, 0);
        gemm16(xn_cur, wt_r1[l], nullptr, Cs, xn_nxt, Ne, 256,
               F_ACC | F_RELU | F_OUTB | F_NOC);

        u16* t;
        t = xs_cur; xs_cur = xs_nxt; xs_nxt = t;
        t = xn_cur; xn_cur = xn_nxt; xn_nxt = t;
    }

    // ---- attentive pooling ----
    gemm16(ch_b,   wt_attc, nullptr, c_att, nullptr, B,  256, 0);
    gemm16(xs_cur, wt_atts, nullptr, Cs,    nullptr, Ns, 256, 0);   // s_att in Cs
    scores_kernel<<<(unsigned)(((long long)Ns * 64 + 255) / 256), 256, 0, stream>>>(
        Cs, c_att, batch_s, scores, Ns);
    pool_kernel<<<B, 256, 0, stream>>>(scores, xs_cur, rp_b, g);

    // ---- head MLP ----
    z_kernel<<<(B * H + 255) / 256, 256, 0, stream>>>(ch, g, z, B, H);
    gemm32(z, wt_w1, b1, hbuf, nullptr, B, 1024, F_RELU);
    out_kernel<<<(B * 2 + 255) / 256, 256, 0, stream>>>(hbuf, W2, b2, (float*)d_out, B, 256);
}

// Round 7
// 1291.767 us; speedup vs baseline: 1.5827x; 1.2773x over previous
//
#include <hip/hip_runtime.h>
#include <hip/hip_bf16.h>
#include <cstddef>

#define F_ACC  1
#define F_RELU 2
#define F_OUTB 4   // also write bf16 mirror Cb
#define F_NOC  8   // skip fp32 C write (C may still be read for F_ACC)

typedef unsigned short u16;
typedef short bf16x8 __attribute__((ext_vector_type(8)));
typedef float f32x4 __attribute__((ext_vector_type(4)));

__device__ inline u16 f2b(float x) {
    union { float f; unsigned u; } c; c.f = x;
    unsigned r = c.u + 0x7FFF + ((c.u >> 16) & 1);
    return (u16)(r >> 16);
}
__device__ inline float b2f(u16 x) {
    union { unsigned u; float f; } c; c.u = ((unsigned)x) << 16;
    return c.f;
}

typedef __attribute__((address_space(3))) unsigned int lds_u32;
typedef __attribute__((address_space(1))) unsigned int glb_u32;
// async global->LDS, 16B per lane; LDS dest = uniform base + lane*16
__device__ inline void glds16(const u16* g, u16* l) {
    __builtin_amdgcn_global_load_lds((const glb_u32*)g, (lds_u32*)l, 16, 0, 0);
}

#define GTM 128
#define GTN 128
#define GBK 64
#define LDA 72   // a32 LDS pad (u16): breaks ds_write bank conflicts

// ---------------- fp32 -> bf16 elementwise (8 elems/thread, grid-stride) ------------
__global__ __launch_bounds__(256) void cvt_b16(
    const float* __restrict__ in, u16* __restrict__ out, long long n8)
{
    long long i = (long long)blockIdx.x * blockDim.x + threadIdx.x;
    const long long stride = (long long)gridDim.x * blockDim.x;
    for (; i < n8; i += stride) {
        float4 a = ((const float4*)in)[i * 2];
        float4 b = ((const float4*)in)[i * 2 + 1];
        ushort4 lo, hi;
        lo.x = f2b(a.x); lo.y = f2b(a.y); lo.z = f2b(a.z); lo.w = f2b(a.w);
        hi.x = f2b(b.x); hi.y = f2b(b.y); hi.z = f2b(b.z); hi.w = f2b(b.w);
        ((ushort4*)out)[i * 2]     = lo;
        ((ushort4*)out)[i * 2 + 1] = hi;
    }
}

// ---------------- GEMM variant 1: fp32 A (cvt staging) — head GEMM only -------------
__global__ __launch_bounds__(256) void gemm_a32(
    const float* __restrict__ A, const u16* __restrict__ Wt,
    const float* __restrict__ bias, float* __restrict__ C, u16* __restrict__ Cb,
    int M, int K, int flags)
{
    __shared__ u16 As[GTM][LDA];
    __shared__ u16 Bs[GTN][LDA];
    const int tid  = threadIdx.x;
    const int bm   = blockIdx.x * GTM;
    const int bn   = blockIdx.y * GTN;
    const int wave = tid >> 6, lane = tid & 63;
    const int wm   = (wave >> 1) * 64, wn = (wave & 1) * 64;
    const int l16  = lane & 15, lq = lane >> 4;
    const int sr   = tid >> 1;
    const int sk   = (tid & 1) * 32;

    f32x4 acc[4][4] = {};

    const int  arow = bm + sr;
    const bool aok  = arow < M;
    const float* Ap = A + (size_t)(aok ? arow : 0) * K + sk;
    const u16*   Wp = Wt + (size_t)(bn + sr) * K + sk;

    for (int k0 = 0; k0 < K; k0 += GBK) {
#pragma unroll
        for (int i = 0; i < 4; ++i) {
            float4 a, b;
            if (aok) {
                a = *(const float4*)(Ap + k0 + i * 8);
                b = *(const float4*)(Ap + k0 + i * 8 + 4);
            } else {
                a = make_float4(0.f, 0.f, 0.f, 0.f);
                b = a;
            }
            ushort4 lo, hi;
            lo.x = f2b(a.x); lo.y = f2b(a.y); lo.z = f2b(a.z); lo.w = f2b(a.w);
            hi.x = f2b(b.x); hi.y = f2b(b.y); hi.z = f2b(b.z); hi.w = f2b(b.w);
            *(ushort4*)&As[sr][sk + i * 8]     = lo;
            *(ushort4*)&As[sr][sk + i * 8 + 4] = hi;
        }
#pragma unroll
        for (int i = 0; i < 4; ++i)
            *(float4*)&Bs[sr][sk + i * 8] = *(const float4*)(Wp + k0 + i * 8);
        __syncthreads();
#pragma unroll
        for (int kk = 0; kk < GBK; kk += 32) {
            bf16x8 af[4], bfr[4];
#pragma unroll
            for (int mt = 0; mt < 4; ++mt)
                af[mt] = *(const bf16x8*)&As[wm + mt * 16 + l16][kk + lq * 8];
#pragma unroll
            for (int nt = 0; nt < 4; ++nt)
                bfr[nt] = *(const bf16x8*)&Bs[wn + nt * 16 + l16][kk + lq * 8];
#pragma unroll
            for (int mt = 0; mt < 4; ++mt)
#pragma unroll
                for (int nt = 0; nt < 4; ++nt)
                    acc[mt][nt] = __builtin_amdgcn_mfma_f32_16x16x32_bf16(
                        af[mt], bfr[nt], acc[mt][nt], 0, 0, 0);
        }
        __syncthreads();
    }

#pragma unroll
    for (int mt = 0; mt < 4; ++mt) {
#pragma unroll
        for (int nt = 0; nt < 4; ++nt) {
            int col = bn + wn + nt * 16 + l16;
            float bv = (bias != nullptr) ? bias[col] : 0.f;
#pragma unroll
            for (int r = 0; r < 4; ++r) {
                int row = bm + wm + mt * 16 + lq * 4 + r;
                if (row >= M) continue;
                float v = acc[mt][nt][r] + bv;
                size_t o = (size_t)row * 256 + col;
                if (flags & F_ACC) v += C[o];
                if (flags & F_RELU) v = fmaxf(v, 0.f);
                if (!(flags & F_NOC)) C[o] = v;
                if (flags & F_OUTB) Cb[o] = f2b(v);
            }
        }
    }
}

// ---------------- GEMM variant 2: bf16 A via global_load_lds (m97 structure) --------
__global__ __launch_bounds__(256) void gemm_a16(
    const u16* __restrict__ A, const u16* __restrict__ Wt,
    const float* __restrict__ bias, float* __restrict__ C, u16* __restrict__ Cb,
    int M, int K, int flags)
{
    __shared__ u16 As[GTM][64];   // linear: required by global_load_lds dest layout
    __shared__ u16 Bs[GTN][64];
    const int tid  = threadIdx.x;
    const int bm   = blockIdx.x * GTM;
    const int bn   = blockIdx.y * GTN;
    const int wave = tid >> 6, lane = tid & 63;
    const int wm   = (wave >> 1) * 64, wn = (wave & 1) * 64;
    const int l16  = lane & 15, lq = lane >> 4;
    const int lrow = lane >> 3;
    const int lcol = (lane & 7) * 8;

    f32x4 acc[4][4] = {};

    for (int k0 = 0; k0 < K; k0 += GBK) {
#pragma unroll
        for (int j = 0; j < 4; ++j) {
            int r  = wave * 32 + j * 8 + lrow;
            int ar = bm + r; if (ar >= M) ar = M - 1;
            glds16(A  + (size_t)ar       * K + k0 + lcol, &As[wave * 32 + j * 8][0]);
            glds16(Wt + (size_t)(bn + r) * K + k0 + lcol, &Bs[wave * 32 + j * 8][0]);
        }
        __syncthreads();
#pragma unroll
        for (int kk = 0; kk < GBK; kk += 32) {
            bf16x8 af[4], bfr[4];
#pragma unroll
            for (int mt = 0; mt < 4; ++mt)
                af[mt] = *(const bf16x8*)&As[wm + mt * 16 + l16][kk + lq * 8];
#pragma unroll
            for (int nt = 0; nt < 4; ++nt)
                bfr[nt] = *(const bf16x8*)&Bs[wn + nt * 16 + l16][kk + lq * 8];
#pragma unroll
            for (int mt = 0; mt < 4; ++mt)
#pragma unroll
                for (int nt = 0; nt < 4; ++nt)
                    acc[mt][nt] = __builtin_amdgcn_mfma_f32_16x16x32_bf16(
                        af[mt], bfr[nt], acc[mt][nt], 0, 0, 0);
        }
        __syncthreads();
    }

#pragma unroll
    for (int mt = 0; mt < 4; ++mt) {
#pragma unroll
        for (int nt = 0; nt < 4; ++nt) {
            int col = bn + wn + nt * 16 + l16;
            float bv = (bias != nullptr) ? bias[col] : 0.f;
#pragma unroll
            for (int r = 0; r < 4; ++r) {
                int row = bm + wm + mt * 16 + lq * 4 + r;
                if (row >= M) continue;
                float v = acc[mt][nt][r] + bv;
                size_t o = (size_t)row * 256 + col;
                if (flags & F_ACC) v += C[o];
                if (flags & F_RELU) v = fmaxf(v, 0.f);
                if (!(flags & F_NOC)) C[o] = v;
                if (flags & F_OUTB) Cb[o] = f2b(v);
            }
        }
    }
}

// ---------------- GEMM variant 3: K-concat of up to 3 bf16 A-parts ------------------
// Each A-part is [M][256] row-major; part p covers K range [p*256,(p+1)*256).
// Wt is [256][K] n-major. Fuses SAGE's (lin_l(mean) + lin_l2(mean2) + lin_r(x)).
__global__ __launch_bounds__(256) void gemm_cat(
    const u16* __restrict__ A0, const u16* __restrict__ A1, const u16* __restrict__ A2,
    const u16* __restrict__ Wt, const float* __restrict__ bias,
    float* __restrict__ C, u16* __restrict__ Cb,
    int M, int K, int flags)
{
    __shared__ u16 As[GTM][64];
    __shared__ u16 Bs[GTN][64];
    const int tid  = threadIdx.x;
    const int bm   = blockIdx.x * GTM;
    const int bn   = blockIdx.y * GTN;
    const int wave = tid >> 6, lane = tid & 63;
    const int wm   = (wave >> 1) * 64, wn = (wave & 1) * 64;
    const int l16  = lane & 15, lq = lane >> 4;
    const int lrow = lane >> 3;
    const int lcol = (lane & 7) * 8;

    f32x4 acc[4][4] = {};

    for (int k0 = 0; k0 < K; k0 += GBK) {
        const int part = k0 >> 8;
        const int ko   = k0 & 255;
        const u16* Ab = (part == 0) ? A0 : ((part == 1) ? A1 : A2);
#pragma unroll
        for (int j = 0; j < 4; ++j) {
            int r  = wave * 32 + j * 8 + lrow;
            int ar = bm + r; if (ar >= M) ar = M - 1;
            glds16(Ab + (size_t)ar       * 256 + ko + lcol, &As[wave * 32 + j * 8][0]);
            glds16(Wt + (size_t)(bn + r) * K   + k0 + lcol, &Bs[wave * 32 + j * 8][0]);
        }
        __syncthreads();
#pragma unroll
        for (int kk = 0; kk < GBK; kk += 32) {
            bf16x8 af[4], bfr[4];
#pragma unroll
            for (int mt = 0; mt < 4; ++mt)
                af[mt] = *(const bf16x8*)&As[wm + mt * 16 + l16][kk + lq * 8];
#pragma unroll
            for (int nt = 0; nt < 4; ++nt)
                bfr[nt] = *(const bf16x8*)&Bs[wn + nt * 16 + l16][kk + lq * 8];
#pragma unroll
            for (int mt = 0; mt < 4; ++mt)
#pragma unroll
                for (int nt = 0; nt < 4; ++nt)
                    acc[mt][nt] = __builtin_amdgcn_mfma_f32_16x16x32_bf16(
                        af[mt], bfr[nt], acc[mt][nt], 0, 0, 0);
        }
        __syncthreads();
    }

#pragma unroll
    for (int mt = 0; mt < 4; ++mt) {
#pragma unroll
        for (int nt = 0; nt < 4; ++nt) {
            int col = bn + wn + nt * 16 + l16;
            float bv = (bias != nullptr) ? bias[col] : 0.f;
#pragma unroll
            for (int r = 0; r < 4; ++r) {
                int row = bm + wm + mt * 16 + lq * 4 + r;
                if (row >= M) continue;
                float v = acc[mt][nt][r] + bv;
                size_t o = (size_t)row * 256 + col;
                if (flags & F_ACC) v += C[o];
                if (flags & F_RELU) v = fmaxf(v, 0.f);
                if (!(flags & F_NOC)) C[o] = v;
                if (flags & F_OUTB) Cb[o] = f2b(v);
            }
        }
    }
}

// W [Kpart,256] fp32 (+optional addend) -> out[n][koff+k] bf16, out is [256][Ktot]
__global__ void pack_wt(const float* __restrict__ W, const float* __restrict__ Wadd,
                        u16* __restrict__ out, int Kpart, int Ktot, int koff)
{
    int idx = blockIdx.x * blockDim.x + threadIdx.x;
    if (idx >= 256 * Kpart) return;
    int n = idx / Kpart, k = idx % Kpart;
    float v = W[(size_t)k * 256 + n];
    if (Wadd) v += Wadd[(size_t)k * 256 + n];
    out[(size_t)n * Ktot + koff + k] = f2b(v);
}

__global__ void vsum_bias(const float* __restrict__ a, const float* __restrict__ b,
                          float* __restrict__ o, int n)
{
    int i = blockIdx.x * blockDim.x + threadIdx.x;
    if (i < n) o[i] = a[i] + b[i];
}

// ---------------- CSR construction ----------------

__global__ void count_edges(const int* __restrict__ dst, int E, int* __restrict__ cnt)
{
    int i = blockIdx.x * blockDim.x + threadIdx.x;
    if (i < E) atomicAdd(&cnt[dst[i]], 1);
}

__global__ void make_inv(const int* __restrict__ cnt, float* __restrict__ inv, int n)
{
    int i = blockIdx.x * blockDim.x + threadIdx.x;
    if (i < n) {
        int c = cnt[i];
        inv[i] = 1.0f / (float)(c > 1 ? c : 1);
    }
}

__global__ void scan1(const int* __restrict__ cnt, int n, int* __restrict__ rowptr,
                      int* __restrict__ bsums)
{
    __shared__ int tmp[256];
    int i = blockIdx.x * 256 + threadIdx.x;
    tmp[threadIdx.x] = (i < n) ? cnt[i] : 0;
    __syncthreads();
    for (int off = 1; off < 256; off <<= 1) {
        int t = (threadIdx.x >= (unsigned)off) ? tmp[threadIdx.x - off] : 0;
        __syncthreads();
        tmp[threadIdx.x] += t;
        __syncthreads();
    }
    if (i < n) rowptr[i + 1] = tmp[threadIdx.x];
    if (threadIdx.x == 255) bsums[blockIdx.x] = tmp[255];
}

__global__ void scan2(int* __restrict__ bsums, int nb)
{
    __shared__ int tmp[256];
    __shared__ int carry;
    if (threadIdx.x == 0) carry = 0;
    __syncthreads();
    for (int base = 0; base < nb; base += 256) {
        int i = base + threadIdx.x;
        tmp[threadIdx.x] = (i < nb) ? bsums[i] : 0;
        __syncthreads();
        for (int off = 1; off < 256; off <<= 1) {
            int t = (threadIdx.x >= (unsigned)off) ? tmp[threadIdx.x - off] : 0;
            __syncthreads();
            tmp[threadIdx.x] += t;
            __syncthreads();
        }
        int c = carry;
        if (i < nb) bsums[i] = tmp[threadIdx.x] + c;
        __syncthreads();
        if (threadIdx.x == 255) carry = c + tmp[255];
        __syncthreads();
    }
}

__global__ void scan3(int* __restrict__ rowptr, const int* __restrict__ bsums, int n)
{
    int i = blockIdx.x * 256 + threadIdx.x;
    if (i == 0) rowptr[0] = 0;
    if (i < n && blockIdx.x > 0) rowptr[i + 1] += bsums[blockIdx.x - 1];
}

__global__ void csr_fill(const int* __restrict__ src, const int* __restrict__ dst, int E,
                         const int* __restrict__ rowptr, int* __restrict__ fillc,
                         int* __restrict__ col)
{
    int e = blockIdx.x * blockDim.x + threadIdx.x;
    if (e < E) {
        int d = dst[e];
        int p = atomicAdd(&fillc[d], 1);
        col[rowptr[d] + p] = src[e];
    }
}

// ---------------- CSR mean-aggregation: bf16 in, fp32 accum, bf16 out ----------------
__global__ __launch_bounds__(256) void gather_mean_b16(
    const u16* __restrict__ X, const int* __restrict__ rowptr,
    const int* __restrict__ col, const float* __restrict__ inv,
    u16* __restrict__ out, int Nd)
{
    long long gid = (long long)blockIdx.x * blockDim.x + threadIdx.x;
    int row = (int)(gid >> 6);
    if (row >= Nd) return;
    int c4 = (threadIdx.x & 63) << 2;
    int e0 = rowptr[row], e1 = rowptr[row + 1];
    float a0 = 0.f, a1 = 0.f, a2 = 0.f, a3 = 0.f;
    int e = e0;
    for (; e + 1 < e1; e += 2) {
        int s0 = col[e], s1 = col[e + 1];
        ushort4 v0 = *(const ushort4*)(X + (size_t)s0 * 256 + c4);
        ushort4 v1 = *(const ushort4*)(X + (size_t)s1 * 256 + c4);
        a0 += b2f(v0.x) + b2f(v1.x); a1 += b2f(v0.y) + b2f(v1.y);
        a2 += b2f(v0.z) + b2f(v1.z); a3 += b2f(v0.w) + b2f(v1.w);
    }
    if (e < e1) {
        int s = col[e];
        ushort4 v = *(const ushort4*)(X + (size_t)s * 256 + c4);
        a0 += b2f(v.x); a1 += b2f(v.y); a2 += b2f(v.z); a3 += b2f(v.w);
    }
    float sc = inv[row];
    ushort4 o;
    o.x = f2b(a0 * sc); o.y = f2b(a1 * sc); o.z = f2b(a2 * sc); o.w = f2b(a3 * sc);
    *(ushort4*)(out + (size_t)row * 256 + c4) = o;
}

// ---------------- attention / pooling (segmented, no atomics) ----------------

__global__ __launch_bounds__(256) void scores_kernel(
    const float* __restrict__ s_att, const float* __restrict__ c_att,
    const int* __restrict__ batch, float* __restrict__ scores, int Ns)
{
    long long gid = (long long)blockIdx.x * blockDim.x + threadIdx.x;
    int row = (int)(gid >> 6);
    if (row >= Ns) return;
    int lane = threadIdx.x & 63;
    int b = batch[row];
    float4 s4 = *(const float4*)(s_att + (size_t)row * 256 + (lane << 2));
    float4 c4 = *(const float4*)(c_att + (size_t)b * 256 + (lane << 2));
    float p = s4.x * c4.x + s4.y * c4.y + s4.z * c4.z + s4.w * c4.w;
#pragma unroll
    for (int off = 32; off > 0; off >>= 1) p += __shfl_down(p, off, 64);
    if (lane == 0) scores[row] = p;
}

__global__ void batch_bounds(const int* __restrict__ batch, int Ns, int B,
                             int* __restrict__ rp)
{
    int i = blockIdx.x * blockDim.x + threadIdx.x;
    if (i > Ns) return;
    if (i == 0) {
        int b1 = batch[0];
        for (int b = 0; b <= b1; ++b) rp[b] = 0;
    } else if (i == Ns) {
        int b0 = batch[Ns - 1];
        for (int b = b0 + 1; b <= B; ++b) rp[b] = Ns;
    } else {
        int b0 = batch[i - 1], b1 = batch[i];
        for (int b = b0 + 1; b <= b1; ++b) rp[b] = i;
    }
}

__global__ __launch_bounds__(256) void pool_kernel(
    float* __restrict__ scores, const u16* __restrict__ xs,
    const int* __restrict__ rp, float* __restrict__ g)
{
    __shared__ float red[256];
    const int b = blockIdx.x, tid = threadIdx.x;
    const int r0 = rp[b], r1 = rp[b + 1];
    if (r0 >= r1) { g[(size_t)b * 256 + tid] = 0.f; return; }
    float m = -3.4e38f;
    for (int r = r0 + tid; r < r1; r += 256) m = fmaxf(m, scores[r]);
    red[tid] = m; __syncthreads();
    for (int s = 128; s > 0; s >>= 1) {
        if (tid < s) red[tid] = fmaxf(red[tid], red[tid + s]);
        __syncthreads();
    }
    m = red[0]; __syncthreads();
    float sum = 0.f;
    for (int r = r0 + tid; r < r1; r += 256) {
        float e = __expf(scores[r] - m);
        scores[r] = e;
        sum += e;
    }
    red[tid] = sum; __syncthreads();
    for (int s = 128; s > 0; s >>= 1) {
        if (tid < s) red[tid] += red[tid + s];
        __syncthreads();
    }
    const float inv = 1.0f / red[0];
    __syncthreads();
    float acc = 0.f;
    for (int r = r0; r < r1; ++r)
        acc += scores[r] * b2f(xs[(size_t)r * 256 + tid]);
    g[(size_t)b * 256 + tid] = acc * inv;
}

__global__ void z_kernel(const float* __restrict__ ch, const float* __restrict__ g,
                         float* __restrict__ z, int B, int H)
{
    int i = blockIdx.x * blockDim.x + threadIdx.x;
    if (i >= B * H) return;
    int b = i / H, c = i % H;
    float cv = ch[i], gv = g[i];
    float* zr = z + (size_t)b * 4 * H;
    zr[c]         = cv;
    zr[H + c]     = gv;
    zr[2 * H + c] = fabsf(cv - gv);
    zr[3 * H + c] = cv * gv;
}

__global__ void out_kernel(const float* __restrict__ h, const float* __restrict__ W2,
                           const float* __restrict__ b2, float* __restrict__ out, int B, int H)
{
    int i = blockIdx.x * blockDim.x + threadIdx.x;
    if (i >= B * 2) return;
    int b = i >> 1, j = i & 1;
    float s = b2[j];
    const float* hr = h + (size_t)b * H;
    for (int k = 0; k < H; ++k) s += hr[k] * W2[k * 2 + j];
    out[i] = s;
}

extern "C" void kernel_launch(void* const* d_in, const int* in_sizes, int n_in,
                              void* d_out, int out_size, void* d_ws, size_t ws_size,
                              hipStream_t stream)
{
    const float* x_s    = (const float*)d_in[0];
    const float* x_n    = (const float*)d_in[1];
    const float* claim  = (const float*)d_in[2];
    const int*   batch_s= (const int*)d_in[3];
    const int*   src_ss = (const int*)d_in[4];
    const int*   dst_ss = (const int*)d_in[5];
    const int*   src_sn = (const int*)d_in[6];
    const int*   dst_sn = (const int*)d_in[7];
    const int*   src_ns = (const int*)d_in[8];
    const int*   dst_ns = (const int*)d_in[9];
    const float* W_ps   = (const float*)d_in[10];
    const float* b_ps   = (const float*)d_in[11];
    const float* W_pn   = (const float*)d_in[12];
    const float* b_pn   = (const float*)d_in[13];
    const float* W_pc   = (const float*)d_in[14];
    const float* b_pc   = (const float*)d_in[15];
    const float* conv_Wl= (const float*)d_in[16];
    const float* conv_bl= (const float*)d_in[17];
    const float* conv_Wr= (const float*)d_in[18];
    const float* W_attc = (const float*)d_in[19];
    const float* W_atts = (const float*)d_in[20];
    const float* W1     = (const float*)d_in[21];
    const float* b1     = (const float*)d_in[22];
    const float* W2     = (const float*)d_in[23];
    const float* b2     = (const float*)d_in[24];

    const int in_dim = 768, H = 256;
    const int Ns  = in_sizes[0] / in_dim;
    const int Ne  = in_sizes[1] / in_dim;
    const int B   = in_sizes[2] / in_dim;
    const int Ess = in_sizes[4];
    const int Esn = in_sizes[6];
    const int Ens = in_sizes[8];
    const int L   = in_sizes[16] / (3 * H * H);
    const int Nmax = (Ns > Ne) ? Ns : Ne;
    const int nb_max = (Nmax + 255) / 256;
    const size_t HH = (size_t)H * H;

    float* ws = (float*)d_ws;
    size_t off = 0;
    auto alloc = [&](size_t n) { float* p = ws + off; off += (n + 63) & ~(size_t)63; return p; };

    // ONE big shared region; users have disjoint lifetimes (stream-serialized):
    //   x_s16 (bf16 [Ns][768])  -> dead after x_s projection
    //   x_n16 (bf16 [Ne][768])  -> converted after x_s proj, dead after x_n proj
    //   mA    (bf16 [Ns][256])  -> gather buffer during layers
    //   Cs    (fp32 [Nmax][256])-> s_att scratch after layers
    size_t rb = (size_t)Ns * 384;
    if ((size_t)Ne * 384   > rb) rb = (size_t)Ne * 384;
    if ((size_t)Nmax * 256 > rb) rb = (size_t)Nmax * 256;
    if ((size_t)Ns * 128   > rb) rb = (size_t)Ns * 128;
    float* RB = alloc(rb);
    u16*   x_s16 = (u16*)RB;
    u16*   x_n16 = (u16*)RB;
    u16*   mA    = (u16*)RB;
    float* Cs    = RB;
    u16* mB      = (u16*)alloc((size_t)Ns * 128);
    u16* claim16 = (u16*)alloc((size_t)B * 384);
    // bf16 activations (u16 [N][256])
    u16* xs_a  = (u16*)alloc((size_t)Ns * 128);
    u16* xs_b  = (u16*)alloc((size_t)Ns * 128);
    u16* xn_a  = (u16*)alloc((size_t)Ne * 128);
    u16* xn_b  = (u16*)alloc((size_t)Ne * 128);
    u16* ch_b  = (u16*)alloc((size_t)B * 128);
    float* ch    = alloc((size_t)B * H);
    float* c_att = alloc((size_t)B * H);
    float* bsum0 = alloc(H);
    float* bsum1 = alloc(H);
    // packed bf16 weights (u16, [256][K] n-major)
    u16* wt_ps   = (u16*)alloc((size_t)256 * 768 / 2);
    u16* wt_pn   = (u16*)alloc((size_t)256 * 768 / 2);
    u16* wt_pc   = (u16*)alloc((size_t)256 * 768 / 2);
    u16* wt_cs_a = (u16*)alloc((size_t)256 * 768 / 2);   // layer0 xs fused [Wl0;Wl2;Wrs]
    u16* wt_cs_b = (u16*)alloc((size_t)256 * 768 / 2);   // layer1
    u16* wt_cn_a = (u16*)alloc((size_t)256 * 512 / 2);   // layer0 xn fused [Wl1;Wr1]
    u16* wt_cn_b = (u16*)alloc((size_t)256 * 512 / 2);   // layer1
    u16* wt_atts = (u16*)alloc(HH / 2);
    u16* wt_attc = (u16*)alloc(HH / 2);
    u16* wt_w1   = (u16*)alloc((size_t)256 * 1024 / 2);
    // CSR
    int*   cnt_ss = (int*)alloc(Ns);
    int*   cnt_sn = (int*)alloc(Ne);
    int*   cnt_ns = (int*)alloc(Ns);
    float* inv_ss = alloc(Ns);
    float* inv_sn = alloc(Ne);
    float* inv_ns = alloc(Ns);
    int*   rp_ss  = (int*)alloc(Ns + 1);
    int*   rp_sn  = (int*)alloc(Ne + 1);
    int*   rp_ns  = (int*)alloc(Ns + 1);
    int*   col_ss = (int*)alloc(Ess);
    int*   col_sn = (int*)alloc(Esn);
    int*   col_ns = (int*)alloc(Ens);
    int*   fillc  = (int*)alloc(Nmax);
    int*   bsums  = (int*)alloc(nb_max);
    // attention / head
    float* scores = alloc(Ns);
    int*   rp_b   = (int*)alloc(B + 1);
    float* g      = alloc((size_t)B * H);
    float* z      = alloc((size_t)B * 4 * H);
    float* hbuf   = alloc((size_t)B * H);
    (void)ws_size; (void)n_in; (void)out_size;

    auto gemm32 = [&](const float* A, const u16* Wt, const float* bias,
                      float* C, u16* Cb, int M, int K, int flags) {
        dim3 grid((M + GTM - 1) / GTM, 2);
        gemm_a32<<<grid, dim3(256), 0, stream>>>(A, Wt, bias, C, Cb, M, K, flags);
    };
    auto gemm16 = [&](const u16* A, const u16* Wt, const float* bias,
                      float* C, u16* Cb, int M, int K, int flags) {
        dim3 grid((M + GTM - 1) / GTM, 2);
        gemm_a16<<<grid, dim3(256), 0, stream>>>(A, Wt, bias, C, Cb, M, K, flags);
    };
    auto gemmcat = [&](const u16* A0, const u16* A1, const u16* A2, const u16* Wt,
                       const float* bias, u16* Cb, int M, int K, int flags) {
        dim3 grid((M + GTM - 1) / GTM, 2);
        gemm_cat<<<grid, dim3(256), 0, stream>>>(A0, A1, A2, Wt, bias, nullptr, Cb,
                                                 M, K, flags);
    };
    auto pack = [&](const float* W, const float* Wadd, u16* o, int Kpart) {
        pack_wt<<<(256 * Kpart + 255) / 256, 256, 0, stream>>>(W, Wadd, o, Kpart, Kpart, 0);
    };
    auto pack_at = [&](const float* W, const float* Wadd, u16* o, int Kpart, int Ktot, int koff) {
        pack_wt<<<(256 * Kpart + 255) / 256, 256, 0, stream>>>(W, Wadd, o, Kpart, Ktot, koff);
    };
    auto cvt = [&](const float* in, u16* o, size_t nelem) {
        long long n8 = (long long)(nelem / 8);
        int nb = (int)((n8 + 255) / 256); if (nb > 2048) nb = 2048;
        cvt_b16<<<nb, 256, 0, stream>>>(in, o, n8);
    };

    // ---- weight packing ----
    pack(W_ps, nullptr, wt_ps, 768);
    pack(W_pn, nullptr, wt_pn, 768);
    pack(W_pc, nullptr, wt_pc, 768);
    u16* wt_cs[2] = {wt_cs_a, wt_cs_b};
    u16* wt_cn[2] = {wt_cn_a, wt_cn_b};
    float* bsum[2] = {bsum0, bsum1};
    for (int l = 0; l < L; ++l) {
        const float* Wl = conv_Wl + (size_t)l * 3 * HH;
        const float* bl = conv_bl + (size_t)l * 3 * H;
        const float* Wr = conv_Wr + (size_t)l * 3 * HH;
        // xs fused: [m_ss | m_ns | xs] @ [Wl_ss ; Wl_ns ; Wr_ss+Wr_ns]
        pack_at(Wl,          nullptr,     wt_cs[l], 256, 768, 0);
        pack_at(Wl + 2 * HH, nullptr,     wt_cs[l], 256, 768, 256);
        pack_at(Wr,          Wr + 2 * HH, wt_cs[l], 256, 768, 512);
        // xn fused: [m_sn | xn] @ [Wl_sn ; Wr_sn]
        pack_at(Wl + HH,     nullptr,     wt_cn[l], 256, 512, 0);
        pack_at(Wr + HH,     nullptr,     wt_cn[l], 256, 512, 256);
        vsum_bias<<<1, 256, 0, stream>>>(bl, bl + 2 * H, bsum[l], H);
    }
    pack(W_atts, nullptr, wt_atts, 256);
    pack(W_attc, nullptr, wt_attc, 256);
    pack(W1,     nullptr, wt_w1, 1024);

    // ---- degree counts + CSR ----
    hipMemsetAsync(cnt_ss, 0, (size_t)Ns * 4, stream);
    hipMemsetAsync(cnt_sn, 0, (size_t)Ne * 4, stream);
    hipMemsetAsync(cnt_ns, 0, (size_t)Ns * 4, stream);
    count_edges<<<(Ess + 255) / 256, 256, 0, stream>>>(dst_ss, Ess, cnt_ss);
    count_edges<<<(Esn + 255) / 256, 256, 0, stream>>>(dst_sn, Esn, cnt_sn);
    count_edges<<<(Ens + 255) / 256, 256, 0, stream>>>(dst_ns, Ens, cnt_ns);
    make_inv<<<(Ns + 255) / 256, 256, 0, stream>>>(cnt_ss, inv_ss, Ns);
    make_inv<<<(Ne + 255) / 256, 256, 0, stream>>>(cnt_sn, inv_sn, Ne);
    make_inv<<<(Ns + 255) / 256, 256, 0, stream>>>(cnt_ns, inv_ns, Ns);
    auto build_csr = [&](const int* src, const int* dst, int E, int Nd,
                         const int* cnt, int* rowptr, int* colidx) {
        int nb = (Nd + 255) / 256;
        scan1<<<nb, 256, 0, stream>>>(cnt, Nd, rowptr, bsums);
        scan2<<<1, 256, 0, stream>>>(bsums, nb);
        scan3<<<nb, 256, 0, stream>>>(rowptr, bsums, Nd);
        hipMemsetAsync(fillc, 0, (size_t)Nd * 4, stream);
        csr_fill<<<(E + 255) / 256, 256, 0, stream>>>(src, dst, E, rowptr, fillc, colidx);
    };
    build_csr(src_ss, dst_ss, Ess, Ns, cnt_ss, rp_ss, col_ss);
    build_csr(src_sn, dst_sn, Esn, Ne, cnt_sn, rp_sn, col_sn);
    build_csr(src_ns, dst_ns, Ens, Ns, cnt_ns, rp_ns, col_ns);

    batch_bounds<<<(Ns + 1 + 255) / 256, 256, 0, stream>>>(batch_s, Ns, B, rp_b);

    // ---- input projections, serialized through the shared region RB ----
    cvt(x_s, x_s16, (size_t)Ns * 768);
    gemm16(x_s16, wt_ps, b_ps, nullptr, xs_a, Ns, 768, F_RELU | F_OUTB | F_NOC);
    cvt(x_n, x_n16, (size_t)Ne * 768);                      // reuses RB after x_s proj
    gemm16(x_n16, wt_pn, b_pn, nullptr, xn_a, Ne, 768, F_RELU | F_OUTB | F_NOC);
    cvt(claim, claim16, (size_t)B * 768);
    gemm16(claim16, wt_pc, b_pc, ch, ch_b, B, 768, F_RELU | F_OUTB);

    // ---- GNN layers: 3 gathers + 2 fused K-concat GEMMs per layer ----
    u16* xs_cur = xs_a; u16* xs_nxt = xs_b;
    u16* xn_cur = xn_a; u16* xn_nxt = xn_b;
    for (int l = 0; l < L; ++l) {
        const float* bl = conv_bl + (size_t)l * 3 * H;

        gather_mean_b16<<<(unsigned)(((long long)Ns * 64 + 255) / 256), 256, 0, stream>>>(
            xs_cur, rp_ss, col_ss, inv_ss, mA, Ns);
        gather_mean_b16<<<(unsigned)(((long long)Ns * 64 + 255) / 256), 256, 0, stream>>>(
            xn_cur, rp_ns, col_ns, inv_ns, mB, Ns);
        gemmcat(mA, mB, xs_cur, wt_cs[l], bsum[l], xs_nxt, Ns, 768,
                F_RELU | F_OUTB | F_NOC);

        gather_mean_b16<<<(unsigned)(((long long)Ne * 64 + 255) / 256), 256, 0, stream>>>(
            xs_cur, rp_sn, col_sn, inv_sn, mA, Ne);
        gemmcat(mA, xn_cur, nullptr, wt_cn[l], bl + H, xn_nxt, Ne, 512,
                F_RELU | F_OUTB | F_NOC);

        u16* t;
        t = xs_cur; xs_cur = xs_nxt; xs_nxt = t;
        t = xn_cur; xn_cur = xn_nxt; xn_nxt = t;
    }

    // ---- attentive pooling (Cs aliases RB; mA dead by now) ----
    gemm16(ch_b,   wt_attc, nullptr, c_att, nullptr, B,  256, 0);
    gemm16(xs_cur, wt_atts, nullptr, Cs,    nullptr, Ns, 256, 0);   // s_att in Cs
    scores_kernel<<<(unsigned)(((long long)Ns * 64 + 255) / 256), 256, 0, stream>>>(
        Cs, c_att, batch_s, scores, Ns);
    pool_kernel<<<B, 256, 0, stream>>>(scores, xs_cur, rp_b, g);

    // ---- head MLP ----
    z_kernel<<<(B * H + 255) / 256, 256, 0, stream>>>(ch, g, z, B, H);
    gemm32(z, wt_w1, b1, hbuf, nullptr, B, 1024, F_RELU);
    out_kernel<<<(B * 2 + 255) / 256, 256, 0, stream>>>(hbuf, W2, b2, (float*)d_out, B, 256);
}

// Round 8
// 1209.839 us; speedup vs baseline: 1.6899x; 1.0677x over previous
//
#include <hip/hip_runtime.h>
#include <hip/hip_bf16.h>
#include <cstddef>

#define F_ACC  1
#define F_RELU 2
#define F_OUTB 4   // also write bf16 mirror Cb
#define F_NOC  8   // skip fp32 C write (C may still be read for F_ACC)

typedef unsigned short u16;
typedef short bf16x8 __attribute__((ext_vector_type(8)));
typedef float f32x4 __attribute__((ext_vector_type(4)));

__device__ inline u16 f2b(float x) {
    union { float f; unsigned u; } c; c.f = x;
    unsigned r = c.u + 0x7FFF + ((c.u >> 16) & 1);
    return (u16)(r >> 16);
}
__device__ inline float b2f(u16 x) {
    union { unsigned u; float f; } c; c.u = ((unsigned)x) << 16;
    return c.f;
}

typedef __attribute__((address_space(3))) unsigned int lds_u32;
typedef __attribute__((address_space(1))) unsigned int glb_u32;
// async global->LDS, 16B per lane; LDS dest = uniform base + lane*16
__device__ inline void glds16(const u16* g, u16* l) {
    __builtin_amdgcn_global_load_lds((const glb_u32*)g, (lds_u32*)l, 16, 0, 0);
}

#define GTM 128
#define GTN 128
#define GBK 64
#define LDA 72   // a32 LDS pad (u16): breaks ds_write bank conflicts

// ---------------- fp32 -> bf16 elementwise (8 elems/thread, grid-stride) ------------
__global__ __launch_bounds__(256) void cvt_b16(
    const float* __restrict__ in, u16* __restrict__ out, long long n8)
{
    long long i = (long long)blockIdx.x * blockDim.x + threadIdx.x;
    const long long stride = (long long)gridDim.x * blockDim.x;
    for (; i < n8; i += stride) {
        float4 a = ((const float4*)in)[i * 2];
        float4 b = ((const float4*)in)[i * 2 + 1];
        ushort4 lo, hi;
        lo.x = f2b(a.x); lo.y = f2b(a.y); lo.z = f2b(a.z); lo.w = f2b(a.w);
        hi.x = f2b(b.x); hi.y = f2b(b.y); hi.z = f2b(b.z); hi.w = f2b(b.w);
        ((ushort4*)out)[i * 2]     = lo;
        ((ushort4*)out)[i * 2 + 1] = hi;
    }
}

// ---------------- GEMM variant 1: fp32 A (cvt staging) — head GEMM only -------------
__global__ __launch_bounds__(256) void gemm_a32(
    const float* __restrict__ A, const u16* __restrict__ Wt,
    const float* __restrict__ bias, float* __restrict__ C, u16* __restrict__ Cb,
    int M, int K, int flags)
{
    __shared__ u16 As[GTM][LDA];
    __shared__ u16 Bs[GTN][LDA];
    const int tid  = threadIdx.x;
    const int bm   = blockIdx.x * GTM;
    const int bn   = blockIdx.y * GTN;
    const int wave = tid >> 6, lane = tid & 63;
    const int wm   = (wave >> 1) * 64, wn = (wave & 1) * 64;
    const int l16  = lane & 15, lq = lane >> 4;
    const int sr   = tid >> 1;
    const int sk   = (tid & 1) * 32;

    f32x4 acc[4][4] = {};

    const int  arow = bm + sr;
    const bool aok  = arow < M;
    const float* Ap = A + (size_t)(aok ? arow : 0) * K + sk;
    const u16*   Wp = Wt + (size_t)(bn + sr) * K + sk;

    for (int k0 = 0; k0 < K; k0 += GBK) {
#pragma unroll
        for (int i = 0; i < 4; ++i) {
            float4 a, b;
            if (aok) {
                a = *(const float4*)(Ap + k0 + i * 8);
                b = *(const float4*)(Ap + k0 + i * 8 + 4);
            } else {
                a = make_float4(0.f, 0.f, 0.f, 0.f);
                b = a;
            }
            ushort4 lo, hi;
            lo.x = f2b(a.x); lo.y = f2b(a.y); lo.z = f2b(a.z); lo.w = f2b(a.w);
            hi.x = f2b(b.x); hi.y = f2b(b.y); hi.z = f2b(b.z); hi.w = f2b(b.w);
            *(ushort4*)&As[sr][sk + i * 8]     = lo;
            *(ushort4*)&As[sr][sk + i * 8 + 4] = hi;
        }
#pragma unroll
        for (int i = 0; i < 4; ++i)
            *(float4*)&Bs[sr][sk + i * 8] = *(const float4*)(Wp + k0 + i * 8);
        __syncthreads();
#pragma unroll
        for (int kk = 0; kk < GBK; kk += 32) {
            bf16x8 af[4], bfr[4];
#pragma unroll
            for (int mt = 0; mt < 4; ++mt)
                af[mt] = *(const bf16x8*)&As[wm + mt * 16 + l16][kk + lq * 8];
#pragma unroll
            for (int nt = 0; nt < 4; ++nt)
                bfr[nt] = *(const bf16x8*)&Bs[wn + nt * 16 + l16][kk + lq * 8];
#pragma unroll
            for (int mt = 0; mt < 4; ++mt)
#pragma unroll
                for (int nt = 0; nt < 4; ++nt)
                    acc[mt][nt] = __builtin_amdgcn_mfma_f32_16x16x32_bf16(
                        af[mt], bfr[nt], acc[mt][nt], 0, 0, 0);
        }
        __syncthreads();
    }

#pragma unroll
    for (int mt = 0; mt < 4; ++mt) {
#pragma unroll
        for (int nt = 0; nt < 4; ++nt) {
            int col = bn + wn + nt * 16 + l16;
            float bv = (bias != nullptr) ? bias[col] : 0.f;
#pragma unroll
            for (int r = 0; r < 4; ++r) {
                int row = bm + wm + mt * 16 + lq * 4 + r;
                if (row >= M) continue;
                float v = acc[mt][nt][r] + bv;
                size_t o = (size_t)row * 256 + col;
                if (flags & F_ACC) v += C[o];
                if (flags & F_RELU) v = fmaxf(v, 0.f);
                if (!(flags & F_NOC)) C[o] = v;
                if (flags & F_OUTB) Cb[o] = f2b(v);
            }
        }
    }
}

// ---------------- GEMM variant 2: bf16 A via global_load_lds (m97 structure) --------
__global__ __launch_bounds__(256) void gemm_a16(
    const u16* __restrict__ A, const u16* __restrict__ Wt,
    const float* __restrict__ bias, float* __restrict__ C, u16* __restrict__ Cb,
    int M, int K, int flags)
{
    __shared__ u16 As[GTM][64];   // linear: required by global_load_lds dest layout
    __shared__ u16 Bs[GTN][64];
    const int tid  = threadIdx.x;
    const int bm   = blockIdx.x * GTM;
    const int bn   = blockIdx.y * GTN;
    const int wave = tid >> 6, lane = tid & 63;
    const int wm   = (wave >> 1) * 64, wn = (wave & 1) * 64;
    const int l16  = lane & 15, lq = lane >> 4;
    const int lrow = lane >> 3;
    const int lcol = (lane & 7) * 8;

    f32x4 acc[4][4] = {};

    for (int k0 = 0; k0 < K; k0 += GBK) {
#pragma unroll
        for (int j = 0; j < 4; ++j) {
            int r  = wave * 32 + j * 8 + lrow;
            int ar = bm + r; if (ar >= M) ar = M - 1;
            glds16(A  + (size_t)ar       * K + k0 + lcol, &As[wave * 32 + j * 8][0]);
            glds16(Wt + (size_t)(bn + r) * K + k0 + lcol, &Bs[wave * 32 + j * 8][0]);
        }
        __syncthreads();
#pragma unroll
        for (int kk = 0; kk < GBK; kk += 32) {
            bf16x8 af[4], bfr[4];
#pragma unroll
            for (int mt = 0; mt < 4; ++mt)
                af[mt] = *(const bf16x8*)&As[wm + mt * 16 + l16][kk + lq * 8];
#pragma unroll
            for (int nt = 0; nt < 4; ++nt)
                bfr[nt] = *(const bf16x8*)&Bs[wn + nt * 16 + l16][kk + lq * 8];
#pragma unroll
            for (int mt = 0; mt < 4; ++mt)
#pragma unroll
                for (int nt = 0; nt < 4; ++nt)
                    acc[mt][nt] = __builtin_amdgcn_mfma_f32_16x16x32_bf16(
                        af[mt], bfr[nt], acc[mt][nt], 0, 0, 0);
        }
        __syncthreads();
    }

#pragma unroll
    for (int mt = 0; mt < 4; ++mt) {
#pragma unroll
        for (int nt = 0; nt < 4; ++nt) {
            int col = bn + wn + nt * 16 + l16;
            float bv = (bias != nullptr) ? bias[col] : 0.f;
#pragma unroll
            for (int r = 0; r < 4; ++r) {
                int row = bm + wm + mt * 16 + lq * 4 + r;
                if (row >= M) continue;
                float v = acc[mt][nt][r] + bv;
                size_t o = (size_t)row * 256 + col;
                if (flags & F_ACC) v += C[o];
                if (flags & F_RELU) v = fmaxf(v, 0.f);
                if (!(flags & F_NOC)) C[o] = v;
                if (flags & F_OUTB) Cb[o] = f2b(v);
            }
        }
    }
}

// ---------------- GEMM variant 3: K-concat of up to 3 bf16 A-parts ------------------
// Each A-part is [M][256] row-major; part p covers K range [p*256,(p+1)*256).
// Wt is [256][K] n-major. Fuses SAGE's (lin_l(mean) + lin_l2(mean2) + lin_r(x)).
__global__ __launch_bounds__(256) void gemm_cat(
    const u16* __restrict__ A0, const u16* __restrict__ A1, const u16* __restrict__ A2,
    const u16* __restrict__ Wt, const float* __restrict__ bias,
    float* __restrict__ C, u16* __restrict__ Cb,
    int M, int K, int flags)
{
    __shared__ u16 As[GTM][64];
    __shared__ u16 Bs[GTN][64];
    const int tid  = threadIdx.x;
    const int bm   = blockIdx.x * GTM;
    const int bn   = blockIdx.y * GTN;
    const int wave = tid >> 6, lane = tid & 63;
    const int wm   = (wave >> 1) * 64, wn = (wave & 1) * 64;
    const int l16  = lane & 15, lq = lane >> 4;
    const int lrow = lane >> 3;
    const int lcol = (lane & 7) * 8;

    f32x4 acc[4][4] = {};

    for (int k0 = 0; k0 < K; k0 += GBK) {
        const int part = k0 >> 8;
        const int ko   = k0 & 255;
        const u16* Ab = (part == 0) ? A0 : ((part == 1) ? A1 : A2);
#pragma unroll
        for (int j = 0; j < 4; ++j) {
            int r  = wave * 32 + j * 8 + lrow;
            int ar = bm + r; if (ar >= M) ar = M - 1;
            glds16(Ab + (size_t)ar       * 256 + ko + lcol, &As[wave * 32 + j * 8][0]);
            glds16(Wt + (size_t)(bn + r) * K   + k0 + lcol, &Bs[wave * 32 + j * 8][0]);
        }
        __syncthreads();
#pragma unroll
        for (int kk = 0; kk < GBK; kk += 32) {
            bf16x8 af[4], bfr[4];
#pragma unroll
            for (int mt = 0; mt < 4; ++mt)
                af[mt] = *(const bf16x8*)&As[wm + mt * 16 + l16][kk + lq * 8];
#pragma unroll
            for (int nt = 0; nt < 4; ++nt)
                bfr[nt] = *(const bf16x8*)&Bs[wn + nt * 16 + l16][kk + lq * 8];
#pragma unroll
            for (int mt = 0; mt < 4; ++mt)
#pragma unroll
                for (int nt = 0; nt < 4; ++nt)
                    acc[mt][nt] = __builtin_amdgcn_mfma_f32_16x16x32_bf16(
                        af[mt], bfr[nt], acc[mt][nt], 0, 0, 0);
        }
        __syncthreads();
    }

#pragma unroll
    for (int mt = 0; mt < 4; ++mt) {
#pragma unroll
        for (int nt = 0; nt < 4; ++nt) {
            int col = bn + wn + nt * 16 + l16;
            float bv = (bias != nullptr) ? bias[col] : 0.f;
#pragma unroll
            for (int r = 0; r < 4; ++r) {
                int row = bm + wm + mt * 16 + lq * 4 + r;
                if (row >= M) continue;
                float v = acc[mt][nt][r] + bv;
                size_t o = (size_t)row * 256 + col;
                if (flags & F_ACC) v += C[o];
                if (flags & F_RELU) v = fmaxf(v, 0.f);
                if (!(flags & F_NOC)) C[o] = v;
                if (flags & F_OUTB) Cb[o] = f2b(v);
            }
        }
    }
}

// W [Kpart,256] fp32 (+optional addend) -> out[n][koff+k] bf16, out is [256][Ktot]
__global__ void pack_wt(const float* __restrict__ W, const float* __restrict__ Wadd,
                        u16* __restrict__ out, int Kpart, int Ktot, int koff)
{
    int idx = blockIdx.x * blockDim.x + threadIdx.x;
    if (idx >= 256 * Kpart) return;
    int n = idx / Kpart, k = idx % Kpart;
    float v = W[(size_t)k * 256 + n];
    if (Wadd) v += Wadd[(size_t)k * 256 + n];
    out[(size_t)n * Ktot + koff + k] = f2b(v);
}

__global__ void vsum_bias(const float* __restrict__ a, const float* __restrict__ b,
                          float* __restrict__ o, int n)
{
    int i = blockIdx.x * blockDim.x + threadIdx.x;
    if (i < n) o[i] = a[i] + b[i];
}

// ---------------- CSR construction ----------------

__global__ void count_edges(const int* __restrict__ dst, int E, int* __restrict__ cnt)
{
    int i = blockIdx.x * blockDim.x + threadIdx.x;
    if (i < E) atomicAdd(&cnt[dst[i]], 1);
}

__global__ void make_inv(const int* __restrict__ cnt, float* __restrict__ inv, int n)
{
    int i = blockIdx.x * blockDim.x + threadIdx.x;
    if (i < n) {
        int c = cnt[i];
        inv[i] = 1.0f / (float)(c > 1 ? c : 1);
    }
}

__global__ void scan1(const int* __restrict__ cnt, int n, int* __restrict__ rowptr,
                      int* __restrict__ bsums)
{
    __shared__ int tmp[256];
    int i = blockIdx.x * 256 + threadIdx.x;
    tmp[threadIdx.x] = (i < n) ? cnt[i] : 0;
    __syncthreads();
    for (int off = 1; off < 256; off <<= 1) {
        int t = (threadIdx.x >= (unsigned)off) ? tmp[threadIdx.x - off] : 0;
        __syncthreads();
        tmp[threadIdx.x] += t;
        __syncthreads();
    }
    if (i < n) rowptr[i + 1] = tmp[threadIdx.x];
    if (threadIdx.x == 255) bsums[blockIdx.x] = tmp[255];
}

__global__ void scan2(int* __restrict__ bsums, int nb)
{
    __shared__ int tmp[256];
    __shared__ int carry;
    if (threadIdx.x == 0) carry = 0;
    __syncthreads();
    for (int base = 0; base < nb; base += 256) {
        int i = base + threadIdx.x;
        tmp[threadIdx.x] = (i < nb) ? bsums[i] : 0;
        __syncthreads();
        for (int off = 1; off < 256; off <<= 1) {
            int t = (threadIdx.x >= (unsigned)off) ? tmp[threadIdx.x - off] : 0;
            __syncthreads();
            tmp[threadIdx.x] += t;
            __syncthreads();
        }
        int c = carry;
        if (i < nb) bsums[i] = tmp[threadIdx.x] + c;
        __syncthreads();
        if (threadIdx.x == 255) carry = c + tmp[255];
        __syncthreads();
    }
}

__global__ void scan3(int* __restrict__ rowptr, const int* __restrict__ bsums, int n)
{
    int i = blockIdx.x * 256 + threadIdx.x;
    if (i == 0) rowptr[0] = 0;
    if (i < n && blockIdx.x > 0) rowptr[i + 1] += bsums[blockIdx.x - 1];
}

__global__ void csr_fill(const int* __restrict__ src, const int* __restrict__ dst, int E,
                         const int* __restrict__ rowptr, int* __restrict__ fillc,
                         int* __restrict__ col)
{
    int e = blockIdx.x * blockDim.x + threadIdx.x;
    if (e < E) {
        int d = dst[e];
        int p = atomicAdd(&fillc[d], 1);
        col[rowptr[d] + p] = src[e];
    }
}

// ---------------- CSR mean-aggregation: bf16 in, fp32 accum, bf16 out ----------------
__global__ __launch_bounds__(256) void gather_mean_b16(
    const u16* __restrict__ X, const int* __restrict__ rowptr,
    const int* __restrict__ col, const float* __restrict__ inv,
    u16* __restrict__ out, int Nd)
{
    long long gid = (long long)blockIdx.x * blockDim.x + threadIdx.x;
    int row = (int)(gid >> 6);
    if (row >= Nd) return;
    int c4 = (threadIdx.x & 63) << 2;
    int e0 = rowptr[row], e1 = rowptr[row + 1];
    float a0 = 0.f, a1 = 0.f, a2 = 0.f, a3 = 0.f;
    int e = e0;
    for (; e + 1 < e1; e += 2) {
        int s0 = col[e], s1 = col[e + 1];
        ushort4 v0 = *(const ushort4*)(X + (size_t)s0 * 256 + c4);
        ushort4 v1 = *(const ushort4*)(X + (size_t)s1 * 256 + c4);
        a0 += b2f(v0.x) + b2f(v1.x); a1 += b2f(v0.y) + b2f(v1.y);
        a2 += b2f(v0.z) + b2f(v1.z); a3 += b2f(v0.w) + b2f(v1.w);
    }
    if (e < e1) {
        int s = col[e];
        ushort4 v = *(const ushort4*)(X + (size_t)s * 256 + c4);
        a0 += b2f(v.x); a1 += b2f(v.y); a2 += b2f(v.z); a3 += b2f(v.w);
    }
    float sc = inv[row];
    ushort4 o;
    o.x = f2b(a0 * sc); o.y = f2b(a1 * sc); o.z = f2b(a2 * sc); o.w = f2b(a3 * sc);
    *(ushort4*)(out + (size_t)row * 256 + c4) = o;
}

// ---------------- attention / pooling (segmented, no atomics) ----------------

__global__ __launch_bounds__(256) void scores_kernel(
    const float* __restrict__ s_att, const float* __restrict__ c_att,
    const int* __restrict__ batch, float* __restrict__ scores, int Ns)
{
    long long gid = (long long)blockIdx.x * blockDim.x + threadIdx.x;
    int row = (int)(gid >> 6);
    if (row >= Ns) return;
    int lane = threadIdx.x & 63;
    int b = batch[row];
    float4 s4 = *(const float4*)(s_att + (size_t)row * 256 + (lane << 2));
    float4 c4 = *(const float4*)(c_att + (size_t)b * 256 + (lane << 2));
    float p = s4.x * c4.x + s4.y * c4.y + s4.z * c4.z + s4.w * c4.w;
#pragma unroll
    for (int off = 32; off > 0; off >>= 1) p += __shfl_down(p, off, 64);
    if (lane == 0) scores[row] = p;
}

__global__ void batch_bounds(const int* __restrict__ batch, int Ns, int B,
                             int* __restrict__ rp)
{
    int i = blockIdx.x * blockDim.x + threadIdx.x;
    if (i > Ns) return;
    if (i == 0) {
        int b1 = batch[0];
        for (int b = 0; b <= b1; ++b) rp[b] = 0;
    } else if (i == Ns) {
        int b0 = batch[Ns - 1];
        for (int b = b0 + 1; b <= B; ++b) rp[b] = Ns;
    } else {
        int b0 = batch[i - 1], b1 = batch[i];
        for (int b = b0 + 1; b <= b1; ++b) rp[b] = i;
    }
}

// per-graph softmax over scores: scores <- exp(score-max), invd[b] = 1/sum (0 if empty)
__global__ __launch_bounds__(256) void pool_softmax(
    float* __restrict__ scores, const int* __restrict__ rp, float* __restrict__ invd)
{
    __shared__ float red[256];
    const int b = blockIdx.x, tid = threadIdx.x;
    const int r0 = rp[b], r1 = rp[b + 1];
    if (r0 >= r1) { if (tid == 0) invd[b] = 0.f; return; }
    float m = -3.4e38f;
    for (int r = r0 + tid; r < r1; r += 256) m = fmaxf(m, scores[r]);
    red[tid] = m; __syncthreads();
    for (int s = 128; s > 0; s >>= 1) {
        if (tid < s) red[tid] = fmaxf(red[tid], red[tid + s]);
        __syncthreads();
    }
    m = red[0]; __syncthreads();
    float sum = 0.f;
    for (int r = r0 + tid; r < r1; r += 256) {
        float e = __expf(scores[r] - m);
        scores[r] = e;
        sum += e;
    }
    red[tid] = sum; __syncthreads();
    for (int s = 128; s > 0; s >>= 1) {
        if (tid < s) red[tid] += red[tid + s];
        __syncthreads();
    }
    if (tid == 0) invd[b] = 1.0f / red[0];
}

// weighted column sum: block (b, q) computes g[b][q*64 .. q*64+63].
// 256 threads = 64 cols x 4 row-lanes; 2-way unrolled strided row loop; LDS reduce.
__global__ __launch_bounds__(256) void wsum_kernel(
    const float* __restrict__ scores, const float* __restrict__ invd,
    const u16* __restrict__ xs, const int* __restrict__ rp, float* __restrict__ g)
{
    __shared__ float red[256];
    const int b   = blockIdx.x, q = blockIdx.y;
    const int tid = threadIdx.x;
    const int col = q * 64 + (tid & 63);
    const int rl  = tid >> 6;               // 0..3
    const int r0 = rp[b], r1 = rp[b + 1];
    float acc = 0.f;
    int r = r0 + rl;
    for (; r + 4 < r1; r += 8) {            // 2-way unroll: independent loads
        float a0 = scores[r], a1 = scores[r + 4];
        float v0 = b2f(xs[(size_t)r * 256 + col]);
        float v1 = b2f(xs[(size_t)(r + 4) * 256 + col]);
        acc += a0 * v0 + a1 * v1;
    }
    if (r < r1) acc += scores[r] * b2f(xs[(size_t)r * 256 + col]);
    red[tid] = acc; __syncthreads();
    if (rl == 0) {
        float v = red[tid] + red[tid + 64] + red[tid + 128] + red[tid + 192];
        g[(size_t)b * 256 + col] = v * invd[b];
    }
}

__global__ void z_kernel(const float* __restrict__ ch, const float* __restrict__ g,
                         float* __restrict__ z, int B, int H)
{
    int i = blockIdx.x * blockDim.x + threadIdx.x;
    if (i >= B * H) return;
    int b = i / H, c = i % H;
    float cv = ch[i], gv = g[i];
    float* zr = z + (size_t)b * 4 * H;
    zr[c]         = cv;
    zr[H + c]     = gv;
    zr[2 * H + c] = fabsf(cv - gv);
    zr[3 * H + c] = cv * gv;
}

__global__ void out_kernel(const float* __restrict__ h, const float* __restrict__ W2,
                           const float* __restrict__ b2, float* __restrict__ out, int B, int H)
{
    int i = blockIdx.x * blockDim.x + threadIdx.x;
    if (i >= B * 2) return;
    int b = i >> 1, j = i & 1;
    float s = b2[j];
    const float* hr = h + (size_t)b * H;
    for (int k = 0; k < H; ++k) s += hr[k] * W2[k * 2 + j];
    out[i] = s;
}

extern "C" void kernel_launch(void* const* d_in, const int* in_sizes, int n_in,
                              void* d_out, int out_size, void* d_ws, size_t ws_size,
                              hipStream_t stream)
{
    const float* x_s    = (const float*)d_in[0];
    const float* x_n    = (const float*)d_in[1];
    const float* claim  = (const float*)d_in[2];
    const int*   batch_s= (const int*)d_in[3];
    const int*   src_ss = (const int*)d_in[4];
    const int*   dst_ss = (const int*)d_in[5];
    const int*   src_sn = (const int*)d_in[6];
    const int*   dst_sn = (const int*)d_in[7];
    const int*   src_ns = (const int*)d_in[8];
    const int*   dst_ns = (const int*)d_in[9];
    const float* W_ps   = (const float*)d_in[10];
    const float* b_ps   = (const float*)d_in[11];
    const float* W_pn   = (const float*)d_in[12];
    const float* b_pn   = (const float*)d_in[13];
    const float* W_pc   = (const float*)d_in[14];
    const float* b_pc   = (const float*)d_in[15];
    const float* conv_Wl= (const float*)d_in[16];
    const float* conv_bl= (const float*)d_in[17];
    const float* conv_Wr= (const float*)d_in[18];
    const float* W_attc = (const float*)d_in[19];
    const float* W_atts = (const float*)d_in[20];
    const float* W1     = (const float*)d_in[21];
    const float* b1     = (const float*)d_in[22];
    const float* W2     = (const float*)d_in[23];
    const float* b2     = (const float*)d_in[24];

    const int in_dim = 768, H = 256;
    const int Ns  = in_sizes[0] / in_dim;
    const int Ne  = in_sizes[1] / in_dim;
    const int B   = in_sizes[2] / in_dim;
    const int Ess = in_sizes[4];
    const int Esn = in_sizes[6];
    const int Ens = in_sizes[8];
    const int L   = in_sizes[16] / (3 * H * H);
    const int Nmax = (Ns > Ne) ? Ns : Ne;
    const int nb_max = (Nmax + 255) / 256;
    const size_t HH = (size_t)H * H;

    float* ws = (float*)d_ws;
    size_t off = 0;
    auto alloc = [&](size_t n) { float* p = ws + off; off += (n + 63) & ~(size_t)63; return p; };

    // ONE big shared region; users have disjoint lifetimes (stream-serialized):
    //   x_s16 (bf16 [Ns][768])  -> dead after x_s projection
    //   x_n16 (bf16 [Ne][768])  -> converted after x_s proj, dead after x_n proj
    //   mA    (bf16 [Ns][256])  -> gather buffer during layers
    //   Cs    (fp32 [Nmax][256])-> s_att scratch after layers
    size_t rb = (size_t)Ns * 384;
    if ((size_t)Ne * 384   > rb) rb = (size_t)Ne * 384;
    if ((size_t)Nmax * 256 > rb) rb = (size_t)Nmax * 256;
    if ((size_t)Ns * 128   > rb) rb = (size_t)Ns * 128;
    float* RB = alloc(rb);
    u16*   x_s16 = (u16*)RB;
    u16*   x_n16 = (u16*)RB;
    u16*   mA    = (u16*)RB;
    float* Cs    = RB;
    u16* mB      = (u16*)alloc((size_t)Ns * 128);
    u16* claim16 = (u16*)alloc((size_t)B * 384);
    // bf16 activations (u16 [N][256])
    u16* xs_a  = (u16*)alloc((size_t)Ns * 128);
    u16* xs_b  = (u16*)alloc((size_t)Ns * 128);
    u16* xn_a  = (u16*)alloc((size_t)Ne * 128);
    u16* xn_b  = (u16*)alloc((size_t)Ne * 128);
    u16* ch_b  = (u16*)alloc((size_t)B * 128);
    float* ch    = alloc((size_t)B * H);
    float* c_att = alloc((size_t)B * H);
    float* bsum0 = alloc(H);
    float* bsum1 = alloc(H);
    // packed bf16 weights (u16, [256][K] n-major)
    u16* wt_ps   = (u16*)alloc((size_t)256 * 768 / 2);
    u16* wt_pn   = (u16*)alloc((size_t)256 * 768 / 2);
    u16* wt_pc   = (u16*)alloc((size_t)256 * 768 / 2);
    u16* wt_cs_a = (u16*)alloc((size_t)256 * 768 / 2);   // layer0 xs fused [Wl0;Wl2;Wrs]
    u16* wt_cs_b = (u16*)alloc((size_t)256 * 768 / 2);   // layer1
    u16* wt_cn_a = (u16*)alloc((size_t)256 * 512 / 2);   // layer0 xn fused [Wl1;Wr1]
    u16* wt_cn_b = (u16*)alloc((size_t)256 * 512 / 2);   // layer1
    u16* wt_atts = (u16*)alloc(HH / 2);
    u16* wt_attc = (u16*)alloc(HH / 2);
    u16* wt_w1   = (u16*)alloc((size_t)256 * 1024 / 2);
    // CSR
    int*   cnt_ss = (int*)alloc(Ns);
    int*   cnt_sn = (int*)alloc(Ne);
    int*   cnt_ns = (int*)alloc(Ns);
    float* inv_ss = alloc(Ns);
    float* inv_sn = alloc(Ne);
    float* inv_ns = alloc(Ns);
    int*   rp_ss  = (int*)alloc(Ns + 1);
    int*   rp_sn  = (int*)alloc(Ne + 1);
    int*   rp_ns  = (int*)alloc(Ns + 1);
    int*   col_ss = (int*)alloc(Ess);
    int*   col_sn = (int*)alloc(Esn);
    int*   col_ns = (int*)alloc(Ens);
    int*   fillc  = (int*)alloc(Nmax);
    int*   bsums  = (int*)alloc(nb_max);
    // attention / head
    float* scores = alloc(Ns);
    float* invd   = alloc(B);
    int*   rp_b   = (int*)alloc(B + 1);
    float* g      = alloc((size_t)B * H);
    float* z      = alloc((size_t)B * 4 * H);
    float* hbuf   = alloc((size_t)B * H);
    (void)ws_size; (void)n_in; (void)out_size;

    auto gemm32 = [&](const float* A, const u16* Wt, const float* bias,
                      float* C, u16* Cb, int M, int K, int flags) {
        dim3 grid((M + GTM - 1) / GTM, 2);
        gemm_a32<<<grid, dim3(256), 0, stream>>>(A, Wt, bias, C, Cb, M, K, flags);
    };
    auto gemm16 = [&](const u16* A, const u16* Wt, const float* bias,
                      float* C, u16* Cb, int M, int K, int flags) {
        dim3 grid((M + GTM - 1) / GTM, 2);
        gemm_a16<<<grid, dim3(256), 0, stream>>>(A, Wt, bias, C, Cb, M, K, flags);
    };
    auto gemmcat = [&](const u16* A0, const u16* A1, const u16* A2, const u16* Wt,
                       const float* bias, u16* Cb, int M, int K, int flags) {
        dim3 grid((M + GTM - 1) / GTM, 2);
        gemm_cat<<<grid, dim3(256), 0, stream>>>(A0, A1, A2, Wt, bias, nullptr, Cb,
                                                 M, K, flags);
    };
    auto pack = [&](const float* W, const float* Wadd, u16* o, int Kpart) {
        pack_wt<<<(256 * Kpart + 255) / 256, 256, 0, stream>>>(W, Wadd, o, Kpart, Kpart, 0);
    };
    auto pack_at = [&](const float* W, const float* Wadd, u16* o, int Kpart, int Ktot, int koff) {
        pack_wt<<<(256 * Kpart + 255) / 256, 256, 0, stream>>>(W, Wadd, o, Kpart, Ktot, koff);
    };
    auto cvt = [&](const float* in, u16* o, size_t nelem) {
        long long n8 = (long long)(nelem / 8);
        int nb = (int)((n8 + 255) / 256); if (nb > 2048) nb = 2048;
        cvt_b16<<<nb, 256, 0, stream>>>(in, o, n8);
    };

    // ---- weight packing ----
    pack(W_ps, nullptr, wt_ps, 768);
    pack(W_pn, nullptr, wt_pn, 768);
    pack(W_pc, nullptr, wt_pc, 768);
    u16* wt_cs[2] = {wt_cs_a, wt_cs_b};
    u16* wt_cn[2] = {wt_cn_a, wt_cn_b};
    float* bsum[2] = {bsum0, bsum1};
    for (int l = 0; l < L; ++l) {
        const float* Wl = conv_Wl + (size_t)l * 3 * HH;
        const float* bl = conv_bl + (size_t)l * 3 * H;
        const float* Wr = conv_Wr + (size_t)l * 3 * HH;
        // xs fused: [m_ss | m_ns | xs] @ [Wl_ss ; Wl_ns ; Wr_ss+Wr_ns]
        pack_at(Wl,          nullptr,     wt_cs[l], 256, 768, 0);
        pack_at(Wl + 2 * HH, nullptr,     wt_cs[l], 256, 768, 256);
        pack_at(Wr,          Wr + 2 * HH, wt_cs[l], 256, 768, 512);
        // xn fused: [m_sn | xn] @ [Wl_sn ; Wr_sn]
        pack_at(Wl + HH,     nullptr,     wt_cn[l], 256, 512, 0);
        pack_at(Wr + HH,     nullptr,     wt_cn[l], 256, 512, 256);
        vsum_bias<<<1, 256, 0, stream>>>(bl, bl + 2 * H, bsum[l], H);
    }
    pack(W_atts, nullptr, wt_atts, 256);
    pack(W_attc, nullptr, wt_attc, 256);
    pack(W1,     nullptr, wt_w1, 1024);

    // ---- degree counts + CSR ----
    hipMemsetAsync(cnt_ss, 0, (size_t)Ns * 4, stream);
    hipMemsetAsync(cnt_sn, 0, (size_t)Ne * 4, stream);
    hipMemsetAsync(cnt_ns, 0, (size_t)Ns * 4, stream);
    count_edges<<<(Ess + 255) / 256, 256, 0, stream>>>(dst_ss, Ess, cnt_ss);
    count_edges<<<(Esn + 255) / 256, 256, 0, stream>>>(dst_sn, Esn, cnt_sn);
    count_edges<<<(Ens + 255) / 256, 256, 0, stream>>>(dst_ns, Ens, cnt_ns);
    make_inv<<<(Ns + 255) / 256, 256, 0, stream>>>(cnt_ss, inv_ss, Ns);
    make_inv<<<(Ne + 255) / 256, 256, 0, stream>>>(cnt_sn, inv_sn, Ne);
    make_inv<<<(Ns + 255) / 256, 256, 0, stream>>>(cnt_ns, inv_ns, Ns);
    auto build_csr = [&](const int* src, const int* dst, int E, int Nd,
                         const int* cnt, int* rowptr, int* colidx) {
        int nb = (Nd + 255) / 256;
        scan1<<<nb, 256, 0, stream>>>(cnt, Nd, rowptr, bsums);
        scan2<<<1, 256, 0, stream>>>(bsums, nb);
        scan3<<<nb, 256, 0, stream>>>(rowptr, bsums, Nd);
        hipMemsetAsync(fillc, 0, (size_t)Nd * 4, stream);
        csr_fill<<<(E + 255) / 256, 256, 0, stream>>>(src, dst, E, rowptr, fillc, colidx);
    };
    build_csr(src_ss, dst_ss, Ess, Ns, cnt_ss, rp_ss, col_ss);
    build_csr(src_sn, dst_sn, Esn, Ne, cnt_sn, rp_sn, col_sn);
    build_csr(src_ns, dst_ns, Ens, Ns, cnt_ns, rp_ns, col_ns);

    batch_bounds<<<(Ns + 1 + 255) / 256, 256, 0, stream>>>(batch_s, Ns, B, rp_b);

    // ---- input projections, serialized through the shared region RB ----
    cvt(x_s, x_s16, (size_t)Ns * 768);
    gemm16(x_s16, wt_ps, b_ps, nullptr, xs_a, Ns, 768, F_RELU | F_OUTB | F_NOC);
    cvt(x_n, x_n16, (size_t)Ne * 768);                      // reuses RB after x_s proj
    gemm16(x_n16, wt_pn, b_pn, nullptr, xn_a, Ne, 768, F_RELU | F_OUTB | F_NOC);
    cvt(claim, claim16, (size_t)B * 768);
    gemm16(claim16, wt_pc, b_pc, ch, ch_b, B, 768, F_RELU | F_OUTB);

    // ---- GNN layers: 3 gathers + 2 fused K-concat GEMMs per layer ----
    u16* xs_cur = xs_a; u16* xs_nxt = xs_b;
    u16* xn_cur = xn_a; u16* xn_nxt = xn_b;
    for (int l = 0; l < L; ++l) {
        const float* bl = conv_bl + (size_t)l * 3 * H;

        gather_mean_b16<<<(unsigned)(((long long)Ns * 64 + 255) / 256), 256, 0, stream>>>(
            xs_cur, rp_ss, col_ss, inv_ss, mA, Ns);
        gather_mean_b16<<<(unsigned)(((long long)Ns * 64 + 255) / 256), 256, 0, stream>>>(
            xn_cur, rp_ns, col_ns, inv_ns, mB, Ns);
        gemmcat(mA, mB, xs_cur, wt_cs[l], bsum[l], xs_nxt, Ns, 768,
                F_RELU | F_OUTB | F_NOC);

        gather_mean_b16<<<(unsigned)(((long long)Ne * 64 + 255) / 256), 256, 0, stream>>>(
            xs_cur, rp_sn, col_sn, inv_sn, mA, Ne);
        gemmcat(mA, xn_cur, nullptr, wt_cn[l], bl + H, xn_nxt, Ne, 512,
                F_RELU | F_OUTB | F_NOC);

        u16* t;
        t = xs_cur; xs_cur = xs_nxt; xs_nxt = t;
        t = xn_cur; xn_cur = xn_nxt; xn_nxt = t;
    }

    // ---- attentive pooling (Cs aliases RB; mA dead by now) ----
    gemm16(ch_b,   wt_attc, nullptr, c_att, nullptr, B,  256, 0);
    gemm16(xs_cur, wt_atts, nullptr, Cs,    nullptr, Ns, 256, 0);   // s_att in Cs
    scores_kernel<<<(unsigned)(((long long)Ns * 64 + 255) / 256), 256, 0, stream>>>(
        Cs, c_att, batch_s, scores, Ns);
    pool_softmax<<<B, 256, 0, stream>>>(scores, rp_b, invd);
    wsum_kernel<<<dim3(B, 4), 256, 0, stream>>>(scores, invd, xs_cur, rp_b, g);

    // ---- head MLP ----
    z_kernel<<<(B * H + 255) / 256, 256, 0, stream>>>(ch, g, z, B, H);
    gemm32(z, wt_w1, b1, hbuf, nullptr, B, 1024, F_RELU);
    out_kernel<<<(B * 2 + 255) / 256, 256, 0, stream>>>(hbuf, W2, b2, (float*)d_out, B, 256);
}

// Round 9
// 1175.371 us; speedup vs baseline: 1.7395x; 1.0293x over previous
//
#include <hip/hip_runtime.h>
#include <hip/hip_bf16.h>
#include <cstddef>

#define F_ACC  1
#define F_RELU 2
#define F_OUTB 4   // also write bf16 mirror Cb
#define F_NOC  8   // skip fp32 C write (C may still be read for F_ACC)

typedef unsigned short u16;
typedef short bf16x8 __attribute__((ext_vector_type(8)));
typedef float f32x4 __attribute__((ext_vector_type(4)));

__device__ inline u16 f2b(float x) {
    union { float f; unsigned u; } c; c.f = x;
    unsigned r = c.u + 0x7FFF + ((c.u >> 16) & 1);
    return (u16)(r >> 16);
}
__device__ inline float b2f(u16 x) {
    union { unsigned u; float f; } c; c.u = ((unsigned)x) << 16;
    return c.f;
}

typedef __attribute__((address_space(3))) unsigned int lds_u32;
typedef __attribute__((address_space(1))) unsigned int glb_u32;
// async global->LDS, 16B per lane; LDS dest = uniform base + lane*16
__device__ inline void glds16(const u16* g, u16* l) {
    __builtin_amdgcn_global_load_lds((const glb_u32*)g, (lds_u32*)l, 16, 0, 0);
}

#define GTM 128
#define GTN 128
#define GBK 64
#define LDA 72   // a32 LDS pad (u16): breaks ds_write bank conflicts

// ---------------- fp32 -> bf16 elementwise (8 elems/thread, grid-stride) ------------
__global__ __launch_bounds__(256) void cvt_b16(
    const float* __restrict__ in, u16* __restrict__ out, long long n8)
{
    long long i = (long long)blockIdx.x * blockDim.x + threadIdx.x;
    const long long stride = (long long)gridDim.x * blockDim.x;
    for (; i < n8; i += stride) {
        float4 a = ((const float4*)in)[i * 2];
        float4 b = ((const float4*)in)[i * 2 + 1];
        ushort4 lo, hi;
        lo.x = f2b(a.x); lo.y = f2b(a.y); lo.z = f2b(a.z); lo.w = f2b(a.w);
        hi.x = f2b(b.x); hi.y = f2b(b.y); hi.z = f2b(b.z); hi.w = f2b(b.w);
        ((ushort4*)out)[i * 2]     = lo;
        ((ushort4*)out)[i * 2 + 1] = hi;
    }
}

// ---------------- GEMM variant 1: fp32 A (cvt staging) — head GEMM only -------------
__global__ __launch_bounds__(256) void gemm_a32(
    const float* __restrict__ A, const u16* __restrict__ Wt,
    const float* __restrict__ bias, float* __restrict__ C, u16* __restrict__ Cb,
    int M, int K, int flags)
{
    __shared__ u16 As[GTM][LDA];
    __shared__ u16 Bs[GTN][LDA];
    const int tid  = threadIdx.x;
    const int bm   = blockIdx.x * GTM;
    const int bn   = blockIdx.y * GTN;
    const int wave = tid >> 6, lane = tid & 63;
    const int wm   = (wave >> 1) * 64, wn = (wave & 1) * 64;
    const int l16  = lane & 15, lq = lane >> 4;
    const int sr   = tid >> 1;
    const int sk   = (tid & 1) * 32;

    f32x4 acc[4][4] = {};

    const int  arow = bm + sr;
    const bool aok  = arow < M;
    const float* Ap = A + (size_t)(aok ? arow : 0) * K + sk;
    const u16*   Wp = Wt + (size_t)(bn + sr) * K + sk;

    for (int k0 = 0; k0 < K; k0 += GBK) {
#pragma unroll
        for (int i = 0; i < 4; ++i) {
            float4 a, b;
            if (aok) {
                a = *(const float4*)(Ap + k0 + i * 8);
                b = *(const float4*)(Ap + k0 + i * 8 + 4);
            } else {
                a = make_float4(0.f, 0.f, 0.f, 0.f);
                b = a;
            }
            ushort4 lo, hi;
            lo.x = f2b(a.x); lo.y = f2b(a.y); lo.z = f2b(a.z); lo.w = f2b(a.w);
            hi.x = f2b(b.x); hi.y = f2b(b.y); hi.z = f2b(b.z); hi.w = f2b(b.w);
            *(ushort4*)&As[sr][sk + i * 8]     = lo;
            *(ushort4*)&As[sr][sk + i * 8 + 4] = hi;
        }
#pragma unroll
        for (int i = 0; i < 4; ++i)
            *(float4*)&Bs[sr][sk + i * 8] = *(const float4*)(Wp + k0 + i * 8);
        __syncthreads();
#pragma unroll
        for (int kk = 0; kk < GBK; kk += 32) {
            bf16x8 af[4], bfr[4];
#pragma unroll
            for (int mt = 0; mt < 4; ++mt)
                af[mt] = *(const bf16x8*)&As[wm + mt * 16 + l16][kk + lq * 8];
#pragma unroll
            for (int nt = 0; nt < 4; ++nt)
                bfr[nt] = *(const bf16x8*)&Bs[wn + nt * 16 + l16][kk + lq * 8];
#pragma unroll
            for (int mt = 0; mt < 4; ++mt)
#pragma unroll
                for (int nt = 0; nt < 4; ++nt)
                    acc[mt][nt] = __builtin_amdgcn_mfma_f32_16x16x32_bf16(
                        af[mt], bfr[nt], acc[mt][nt], 0, 0, 0);
        }
        __syncthreads();
    }

#pragma unroll
    for (int mt = 0; mt < 4; ++mt) {
#pragma unroll
        for (int nt = 0; nt < 4; ++nt) {
            int col = bn + wn + nt * 16 + l16;
            float bv = (bias != nullptr) ? bias[col] : 0.f;
#pragma unroll
            for (int r = 0; r < 4; ++r) {
                int row = bm + wm + mt * 16 + lq * 4 + r;
                if (row >= M) continue;
                float v = acc[mt][nt][r] + bv;
                size_t o = (size_t)row * 256 + col;
                if (flags & F_ACC) v += C[o];
                if (flags & F_RELU) v = fmaxf(v, 0.f);
                if (!(flags & F_NOC)) C[o] = v;
                if (flags & F_OUTB) Cb[o] = f2b(v);
            }
        }
    }
}

// ---------------- GEMM variant 2: bf16 A via global_load_lds (m97 structure) --------
__global__ __launch_bounds__(256) void gemm_a16(
    const u16* __restrict__ A, const u16* __restrict__ Wt,
    const float* __restrict__ bias, float* __restrict__ C, u16* __restrict__ Cb,
    int M, int K, int flags)
{
    __shared__ u16 As[GTM][64];   // linear: required by global_load_lds dest layout
    __shared__ u16 Bs[GTN][64];
    const int tid  = threadIdx.x;
    const int bm   = blockIdx.x * GTM;
    const int bn   = blockIdx.y * GTN;
    const int wave = tid >> 6, lane = tid & 63;
    const int wm   = (wave >> 1) * 64, wn = (wave & 1) * 64;
    const int l16  = lane & 15, lq = lane >> 4;
    const int lrow = lane >> 3;
    const int lcol = (lane & 7) * 8;

    f32x4 acc[4][4] = {};

    for (int k0 = 0; k0 < K; k0 += GBK) {
#pragma unroll
        for (int j = 0; j < 4; ++j) {
            int r  = wave * 32 + j * 8 + lrow;
            int ar = bm + r; if (ar >= M) ar = M - 1;
            glds16(A  + (size_t)ar       * K + k0 + lcol, &As[wave * 32 + j * 8][0]);
            glds16(Wt + (size_t)(bn + r) * K + k0 + lcol, &Bs[wave * 32 + j * 8][0]);
        }
        __syncthreads();
#pragma unroll
        for (int kk = 0; kk < GBK; kk += 32) {
            bf16x8 af[4], bfr[4];
#pragma unroll
            for (int mt = 0; mt < 4; ++mt)
                af[mt] = *(const bf16x8*)&As[wm + mt * 16 + l16][kk + lq * 8];
#pragma unroll
            for (int nt = 0; nt < 4; ++nt)
                bfr[nt] = *(const bf16x8*)&Bs[wn + nt * 16 + l16][kk + lq * 8];
#pragma unroll
            for (int mt = 0; mt < 4; ++mt)
#pragma unroll
                for (int nt = 0; nt < 4; ++nt)
                    acc[mt][nt] = __builtin_amdgcn_mfma_f32_16x16x32_bf16(
                        af[mt], bfr[nt], acc[mt][nt], 0, 0, 0);
        }
        __syncthreads();
    }

#pragma unroll
    for (int mt = 0; mt < 4; ++mt) {
#pragma unroll
        for (int nt = 0; nt < 4; ++nt) {
            int col = bn + wn + nt * 16 + l16;
            float bv = (bias != nullptr) ? bias[col] : 0.f;
#pragma unroll
            for (int r = 0; r < 4; ++r) {
                int row = bm + wm + mt * 16 + lq * 4 + r;
                if (row >= M) continue;
                float v = acc[mt][nt][r] + bv;
                size_t o = (size_t)row * 256 + col;
                if (flags & F_ACC) v += C[o];
                if (flags & F_RELU) v = fmaxf(v, 0.f);
                if (!(flags & F_NOC)) C[o] = v;
                if (flags & F_OUTB) Cb[o] = f2b(v);
            }
        }
    }
}

// ---------------- GEMM variant 3: K-concat of up to 3 bf16 A-parts ------------------
__global__ __launch_bounds__(256) void gemm_cat(
    const u16* __restrict__ A0, const u16* __restrict__ A1, const u16* __restrict__ A2,
    const u16* __restrict__ Wt, const float* __restrict__ bias,
    float* __restrict__ C, u16* __restrict__ Cb,
    int M, int K, int flags)
{
    __shared__ u16 As[GTM][64];
    __shared__ u16 Bs[GTN][64];
    const int tid  = threadIdx.x;
    const int bm   = blockIdx.x * GTM;
    const int bn   = blockIdx.y * GTN;
    const int wave = tid >> 6, lane = tid & 63;
    const int wm   = (wave >> 1) * 64, wn = (wave & 1) * 64;
    const int l16  = lane & 15, lq = lane >> 4;
    const int lrow = lane >> 3;
    const int lcol = (lane & 7) * 8;

    f32x4 acc[4][4] = {};

    for (int k0 = 0; k0 < K; k0 += GBK) {
        const int part = k0 >> 8;
        const int ko   = k0 & 255;
        const u16* Ab = (part == 0) ? A0 : ((part == 1) ? A1 : A2);
#pragma unroll
        for (int j = 0; j < 4; ++j) {
            int r  = wave * 32 + j * 8 + lrow;
            int ar = bm + r; if (ar >= M) ar = M - 1;
            glds16(Ab + (size_t)ar       * 256 + ko + lcol, &As[wave * 32 + j * 8][0]);
            glds16(Wt + (size_t)(bn + r) * K   + k0 + lcol, &Bs[wave * 32 + j * 8][0]);
        }
        __syncthreads();
#pragma unroll
        for (int kk = 0; kk < GBK; kk += 32) {
            bf16x8 af[4], bfr[4];
#pragma unroll
            for (int mt = 0; mt < 4; ++mt)
                af[mt] = *(const bf16x8*)&As[wm + mt * 16 + l16][kk + lq * 8];
#pragma unroll
            for (int nt = 0; nt < 4; ++nt)
                bfr[nt] = *(const bf16x8*)&Bs[wn + nt * 16 + l16][kk + lq * 8];
#pragma unroll
            for (int mt = 0; mt < 4; ++mt)
#pragma unroll
                for (int nt = 0; nt < 4; ++nt)
                    acc[mt][nt] = __builtin_amdgcn_mfma_f32_16x16x32_bf16(
                        af[mt], bfr[nt], acc[mt][nt], 0, 0, 0);
        }
        __syncthreads();
    }

#pragma unroll
    for (int mt = 0; mt < 4; ++mt) {
#pragma unroll
        for (int nt = 0; nt < 4; ++nt) {
            int col = bn + wn + nt * 16 + l16;
            float bv = (bias != nullptr) ? bias[col] : 0.f;
#pragma unroll
            for (int r = 0; r < 4; ++r) {
                int row = bm + wm + mt * 16 + lq * 4 + r;
                if (row >= M) continue;
                float v = acc[mt][nt][r] + bv;
                size_t o = (size_t)row * 256 + col;
                if (flags & F_ACC) v += C[o];
                if (flags & F_RELU) v = fmaxf(v, 0.f);
                if (!(flags & F_NOC)) C[o] = v;
                if (flags & F_OUTB) Cb[o] = f2b(v);
            }
        }
    }
}

// W [Kpart,256] fp32 (+optional addend) -> out[n][koff+k] bf16, out is [256][Ktot]
__global__ void pack_wt(const float* __restrict__ W, const float* __restrict__ Wadd,
                        u16* __restrict__ out, int Kpart, int Ktot, int koff)
{
    int idx = blockIdx.x * blockDim.x + threadIdx.x;
    if (idx >= 256 * Kpart) return;
    int n = idx / Kpart, k = idx % Kpart;
    float v = W[(size_t)k * 256 + n];
    if (Wadd) v += Wadd[(size_t)k * 256 + n];
    out[(size_t)n * Ktot + koff + k] = f2b(v);
}

__global__ void vsum_bias(const float* __restrict__ a, const float* __restrict__ b,
                          float* __restrict__ o, int n)
{
    int i = blockIdx.x * blockDim.x + threadIdx.x;
    if (i < n) o[i] = a[i] + b[i];
}

// ---------------- CSR construction ----------------

__global__ void count_edges(const int* __restrict__ dst, int E, int* __restrict__ cnt)
{
    int i = blockIdx.x * blockDim.x + threadIdx.x;
    if (i < E) atomicAdd(&cnt[dst[i]], 1);
}

__global__ void make_inv(const int* __restrict__ cnt, float* __restrict__ inv, int n)
{
    int i = blockIdx.x * blockDim.x + threadIdx.x;
    if (i < n) {
        int c = cnt[i];
        inv[i] = 1.0f / (float)(c > 1 ? c : 1);
    }
}

__global__ void scan1(const int* __restrict__ cnt, int n, int* __restrict__ rowptr,
                      int* __restrict__ bsums)
{
    __shared__ int tmp[256];
    int i = blockIdx.x * 256 + threadIdx.x;
    tmp[threadIdx.x] = (i < n) ? cnt[i] : 0;
    __syncthreads();
    for (int off = 1; off < 256; off <<= 1) {
        int t = (threadIdx.x >= (unsigned)off) ? tmp[threadIdx.x - off] : 0;
        __syncthreads();
        tmp[threadIdx.x] += t;
        __syncthreads();
    }
    if (i < n) rowptr[i + 1] = tmp[threadIdx.x];
    if (threadIdx.x == 255) bsums[blockIdx.x] = tmp[255];
}

__global__ void scan2(int* __restrict__ bsums, int nb)
{
    __shared__ int tmp[256];
    __shared__ int carry;
    if (threadIdx.x == 0) carry = 0;
    __syncthreads();
    for (int base = 0; base < nb; base += 256) {
        int i = base + threadIdx.x;
        tmp[threadIdx.x] = (i < nb) ? bsums[i] : 0;
        __syncthreads();
        for (int off = 1; off < 256; off <<= 1) {
            int t = (threadIdx.x >= (unsigned)off) ? tmp[threadIdx.x - off] : 0;
            __syncthreads();
            tmp[threadIdx.x] += t;
            __syncthreads();
        }
        int c = carry;
        if (i < nb) bsums[i] = tmp[threadIdx.x] + c;
        __syncthreads();
        if (threadIdx.x == 255) carry = c + tmp[255];
        __syncthreads();
    }
}

__global__ void scan3(int* __restrict__ rowptr, const int* __restrict__ bsums, int n)
{
    int i = blockIdx.x * 256 + threadIdx.x;
    if (i == 0) rowptr[0] = 0;
    if (i < n && blockIdx.x > 0) rowptr[i + 1] += bsums[blockIdx.x - 1];
}

__global__ void csr_fill(const int* __restrict__ src, const int* __restrict__ dst, int E,
                         const int* __restrict__ rowptr, int* __restrict__ fillc,
                         int* __restrict__ col)
{
    int e = blockIdx.x * blockDim.x + threadIdx.x;
    if (e < E) {
        int d = dst[e];
        int p = atomicAdd(&fillc[d], 1);
        col[rowptr[d] + p] = src[e];
    }
}

// ---------------- CSR mean-aggregation: bf16 in, fp32 accum, bf16 out ----------------
// 4-way unrolled edge loop: 4 independent row loads in flight per wave.
__global__ __launch_bounds__(256) void gather_mean_b16(
    const u16* __restrict__ X, const int* __restrict__ rowptr,
    const int* __restrict__ col, const float* __restrict__ inv,
    u16* __restrict__ out, int Nd)
{
    long long gid = (long long)blockIdx.x * blockDim.x + threadIdx.x;
    int row = (int)(gid >> 6);
    if (row >= Nd) return;
    int c4 = (threadIdx.x & 63) << 2;
    int e0 = rowptr[row], e1 = rowptr[row + 1];
    float a0 = 0.f, a1 = 0.f, a2 = 0.f, a3 = 0.f;
    int e = e0;
    for (; e + 3 < e1; e += 4) {
        int s0 = col[e], s1 = col[e + 1], s2 = col[e + 2], s3 = col[e + 3];
        ushort4 v0 = *(const ushort4*)(X + (size_t)s0 * 256 + c4);
        ushort4 v1 = *(const ushort4*)(X + (size_t)s1 * 256 + c4);
        ushort4 v2 = *(const ushort4*)(X + (size_t)s2 * 256 + c4);
        ushort4 v3 = *(const ushort4*)(X + (size_t)s3 * 256 + c4);
        a0 += (b2f(v0.x) + b2f(v1.x)) + (b2f(v2.x) + b2f(v3.x));
        a1 += (b2f(v0.y) + b2f(v1.y)) + (b2f(v2.y) + b2f(v3.y));
        a2 += (b2f(v0.z) + b2f(v1.z)) + (b2f(v2.z) + b2f(v3.z));
        a3 += (b2f(v0.w) + b2f(v1.w)) + (b2f(v2.w) + b2f(v3.w));
    }
    for (; e < e1; ++e) {
        int s = col[e];
        ushort4 v = *(const ushort4*)(X + (size_t)s * 256 + c4);
        a0 += b2f(v.x); a1 += b2f(v.y); a2 += b2f(v.z); a3 += b2f(v.w);
    }
    float sc = inv[row];
    ushort4 o;
    o.x = f2b(a0 * sc); o.y = f2b(a1 * sc); o.z = f2b(a2 * sc); o.w = f2b(a3 * sc);
    *(ushort4*)(out + (size_t)row * 256 + c4) = o;
}

// ---------------- attention / pooling (segmented, no atomics) ----------------

// U[b][j] = sum_d c_att[b][d] * W_atts[j][d]   (fp32; W stays fp32 — exact reassoc
// of scores = (xs@Ws)·(ch@Wc) into xs · U[batch])
__global__ __launch_bounds__(256) void att_u(
    const float* __restrict__ c_att, const float* __restrict__ W_atts,
    float* __restrict__ U)
{
    __shared__ float cb[256];
    const int b = blockIdx.x, j = threadIdx.x;
    cb[j] = c_att[(size_t)b * 256 + j];
    __syncthreads();
    const float* wr = W_atts + (size_t)j * 256;
    float s = 0.f;
#pragma unroll 4
    for (int d = 0; d < 256; d += 4) {
        float4 w = *(const float4*)(wr + d);
        s += w.x * cb[d] + w.y * cb[d + 1] + w.z * cb[d + 2] + w.w * cb[d + 3];
    }
    U[(size_t)b * 256 + j] = s;
}

// scores[i] = xs[i,:] · U[batch[i],:] — one wave per row, bf16 xs
__global__ __launch_bounds__(256) void scores2_kernel(
    const u16* __restrict__ xs, const float* __restrict__ U,
    const int* __restrict__ batch, float* __restrict__ scores, int Ns)
{
    long long gid = (long long)blockIdx.x * blockDim.x + threadIdx.x;
    int row = (int)(gid >> 6);
    if (row >= Ns) return;
    int lane = threadIdx.x & 63;
    int b = batch[row];
    ushort4 v = *(const ushort4*)(xs + (size_t)row * 256 + (lane << 2));
    float4  u = *(const float4*)(U + (size_t)b * 256 + (lane << 2));
    float p = b2f(v.x) * u.x + b2f(v.y) * u.y + b2f(v.z) * u.z + b2f(v.w) * u.w;
#pragma unroll
    for (int off = 32; off > 0; off >>= 1) p += __shfl_down(p, off, 64);
    if (lane == 0) scores[row] = p;
}

__global__ void batch_bounds(const int* __restrict__ batch, int Ns, int B,
                             int* __restrict__ rp)
{
    int i = blockIdx.x * blockDim.x + threadIdx.x;
    if (i > Ns) return;
    if (i == 0) {
        int b1 = batch[0];
        for (int b = 0; b <= b1; ++b) rp[b] = 0;
    } else if (i == Ns) {
        int b0 = batch[Ns - 1];
        for (int b = b0 + 1; b <= B; ++b) rp[b] = Ns;
    } else {
        int b0 = batch[i - 1], b1 = batch[i];
        for (int b = b0 + 1; b <= b1; ++b) rp[b] = i;
    }
}

// per-graph softmax over scores: scores <- exp(score-max), invd[b] = 1/sum (0 if empty)
__global__ __launch_bounds__(256) void pool_softmax(
    float* __restrict__ scores, const int* __restrict__ rp, float* __restrict__ invd)
{
    __shared__ float red[256];
    const int b = blockIdx.x, tid = threadIdx.x;
    const int r0 = rp[b], r1 = rp[b + 1];
    if (r0 >= r1) { if (tid == 0) invd[b] = 0.f; return; }
    float m = -3.4e38f;
    for (int r = r0 + tid; r < r1; r += 256) m = fmaxf(m, scores[r]);
    red[tid] = m; __syncthreads();
    for (int s = 128; s > 0; s >>= 1) {
        if (tid < s) red[tid] = fmaxf(red[tid], red[tid + s]);
        __syncthreads();
    }
    m = red[0]; __syncthreads();
    float sum = 0.f;
    for (int r = r0 + tid; r < r1; r += 256) {
        float e = __expf(scores[r] - m);
        scores[r] = e;
        sum += e;
    }
    red[tid] = sum; __syncthreads();
    for (int s = 128; s > 0; s >>= 1) {
        if (tid < s) red[tid] += red[tid + s];
        __syncthreads();
    }
    if (tid == 0) invd[b] = 1.0f / red[0];
}

// weighted column sum: block (b, q) computes g[b][q*64 .. q*64+63].
__global__ __launch_bounds__(256) void wsum_kernel(
    const float* __restrict__ scores, const float* __restrict__ invd,
    const u16* __restrict__ xs, const int* __restrict__ rp, float* __restrict__ g)
{
    __shared__ float red[256];
    const int b   = blockIdx.x, q = blockIdx.y;
    const int tid = threadIdx.x;
    const int col = q * 64 + (tid & 63);
    const int rl  = tid >> 6;               // 0..3
    const int r0 = rp[b], r1 = rp[b + 1];
    float acc = 0.f;
    int r = r0 + rl;
    for (; r + 4 < r1; r += 8) {            // 2-way unroll: independent loads
        float a0 = scores[r], a1 = scores[r + 4];
        float v0 = b2f(xs[(size_t)r * 256 + col]);
        float v1 = b2f(xs[(size_t)(r + 4) * 256 + col]);
        acc += a0 * v0 + a1 * v1;
    }
    if (r < r1) acc += scores[r] * b2f(xs[(size_t)r * 256 + col]);
    red[tid] = acc; __syncthreads();
    if (rl == 0) {
        float v = red[tid] + red[tid + 64] + red[tid + 128] + red[tid + 192];
        g[(size_t)b * 256 + col] = v * invd[b];
    }
}

__global__ void z_kernel(const float* __restrict__ ch, const float* __restrict__ g,
                         float* __restrict__ z, int B, int H)
{
    int i = blockIdx.x * blockDim.x + threadIdx.x;
    if (i >= B * H) return;
    int b = i / H, c = i % H;
    float cv = ch[i], gv = g[i];
    float* zr = z + (size_t)b * 4 * H;
    zr[c]         = cv;
    zr[H + c]     = gv;
    zr[2 * H + c] = fabsf(cv - gv);
    zr[3 * H + c] = cv * gv;
}

__global__ void out_kernel(const float* __restrict__ h, const float* __restrict__ W2,
                           const float* __restrict__ b2, float* __restrict__ out, int B, int H)
{
    int i = blockIdx.x * blockDim.x + threadIdx.x;
    if (i >= B * 2) return;
    int b = i >> 1, j = i & 1;
    float s = b2[j];
    const float* hr = h + (size_t)b * H;
    for (int k = 0; k < H; ++k) s += hr[k] * W2[k * 2 + j];
    out[i] = s;
}

extern "C" void kernel_launch(void* const* d_in, const int* in_sizes, int n_in,
                              void* d_out, int out_size, void* d_ws, size_t ws_size,
                              hipStream_t stream)
{
    const float* x_s    = (const float*)d_in[0];
    const float* x_n    = (const float*)d_in[1];
    const float* claim  = (const float*)d_in[2];
    const int*   batch_s= (const int*)d_in[3];
    const int*   src_ss = (const int*)d_in[4];
    const int*   dst_ss = (const int*)d_in[5];
    const int*   src_sn = (const int*)d_in[6];
    const int*   dst_sn = (const int*)d_in[7];
    const int*   src_ns = (const int*)d_in[8];
    const int*   dst_ns = (const int*)d_in[9];
    const float* W_ps   = (const float*)d_in[10];
    const float* b_ps   = (const float*)d_in[11];
    const float* W_pn   = (const float*)d_in[12];
    const float* b_pn   = (const float*)d_in[13];
    const float* W_pc   = (const float*)d_in[14];
    const float* b_pc   = (const float*)d_in[15];
    const float* conv_Wl= (const float*)d_in[16];
    const float* conv_bl= (const float*)d_in[17];
    const float* conv_Wr= (const float*)d_in[18];
    const float* W_attc = (const float*)d_in[19];
    const float* W_atts = (const float*)d_in[20];
    const float* W1     = (const float*)d_in[21];
    const float* b1     = (const float*)d_in[22];
    const float* W2     = (const float*)d_in[23];
    const float* b2     = (const float*)d_in[24];

    const int in_dim = 768, H = 256;
    const int Ns  = in_sizes[0] / in_dim;
    const int Ne  = in_sizes[1] / in_dim;
    const int B   = in_sizes[2] / in_dim;
    const int Ess = in_sizes[4];
    const int Esn = in_sizes[6];
    const int Ens = in_sizes[8];
    const int L   = in_sizes[16] / (3 * H * H);
    const int Nmax = (Ns > Ne) ? Ns : Ne;
    const int nb_max = (Nmax + 255) / 256;
    const size_t HH = (size_t)H * H;

    float* ws = (float*)d_ws;
    size_t off = 0;
    auto alloc = [&](size_t n) { float* p = ws + off; off += (n + 63) & ~(size_t)63; return p; };

    // ONE big shared region; users have disjoint lifetimes (stream-serialized):
    //   x_s16 (bf16 [Ns][768])  -> dead after x_s projection
    //   x_n16 (bf16 [Ne][768])  -> converted after x_s proj, dead after x_n proj
    //   mA    (bf16 [Ns][256])  -> gather buffer during layers
    size_t rb = (size_t)Ns * 384;
    if ((size_t)Ne * 384   > rb) rb = (size_t)Ne * 384;
    if ((size_t)Nmax * 256 > rb) rb = (size_t)Nmax * 256;
    if ((size_t)Ns * 128   > rb) rb = (size_t)Ns * 128;
    float* RB = alloc(rb);
    u16*   x_s16 = (u16*)RB;
    u16*   x_n16 = (u16*)RB;
    u16*   mA    = (u16*)RB;
    u16* mB      = (u16*)alloc((size_t)Ns * 128);
    u16* claim16 = (u16*)alloc((size_t)B * 384);
    // bf16 activations (u16 [N][256])
    u16* xs_a  = (u16*)alloc((size_t)Ns * 128);
    u16* xs_b  = (u16*)alloc((size_t)Ns * 128);
    u16* xn_a  = (u16*)alloc((size_t)Ne * 128);
    u16* xn_b  = (u16*)alloc((size_t)Ne * 128);
    u16* ch_b  = (u16*)alloc((size_t)B * 128);
    float* ch    = alloc((size_t)B * H);
    float* c_att = alloc((size_t)B * H);
    float* Uatt  = alloc((size_t)B * H);
    float* bsum0 = alloc(H);
    float* bsum1 = alloc(H);
    // packed bf16 weights (u16, [256][K] n-major)
    u16* wt_ps   = (u16*)alloc((size_t)256 * 768 / 2);
    u16* wt_pn   = (u16*)alloc((size_t)256 * 768 / 2);
    u16* wt_pc   = (u16*)alloc((size_t)256 * 768 / 2);
    u16* wt_cs_a = (u16*)alloc((size_t)256 * 768 / 2);   // layer0 xs fused [Wl0;Wl2;Wrs]
    u16* wt_cs_b = (u16*)alloc((size_t)256 * 768 / 2);   // layer1
    u16* wt_cn_a = (u16*)alloc((size_t)256 * 512 / 2);   // layer0 xn fused [Wl1;Wr1]
    u16* wt_cn_b = (u16*)alloc((size_t)256 * 512 / 2);   // layer1
    u16* wt_attc = (u16*)alloc(HH / 2);
    u16* wt_w1   = (u16*)alloc((size_t)256 * 1024 / 2);
    // CSR
    int*   cnt_ss = (int*)alloc(Ns);
    int*   cnt_sn = (int*)alloc(Ne);
    int*   cnt_ns = (int*)alloc(Ns);
    float* inv_ss = alloc(Ns);
    float* inv_sn = alloc(Ne);
    float* inv_ns = alloc(Ns);
    int*   rp_ss  = (int*)alloc(Ns + 1);
    int*   rp_sn  = (int*)alloc(Ne + 1);
    int*   rp_ns  = (int*)alloc(Ns + 1);
    int*   col_ss = (int*)alloc(Ess);
    int*   col_sn = (int*)alloc(Esn);
    int*   col_ns = (int*)alloc(Ens);
    int*   fillc  = (int*)alloc(Nmax);
    int*   bsums  = (int*)alloc(nb_max);
    // attention / head
    float* scores = alloc(Ns);
    float* invd   = alloc(B);
    int*   rp_b   = (int*)alloc(B + 1);
    float* g      = alloc((size_t)B * H);
    float* z      = alloc((size_t)B * 4 * H);
    float* hbuf   = alloc((size_t)B * H);
    (void)ws_size; (void)n_in; (void)out_size;

    auto gemm32 = [&](const float* A, const u16* Wt, const float* bias,
                      float* C, u16* Cb, int M, int K, int flags) {
        dim3 grid((M + GTM - 1) / GTM, 2);
        gemm_a32<<<grid, dim3(256), 0, stream>>>(A, Wt, bias, C, Cb, M, K, flags);
    };
    auto gemm16 = [&](const u16* A, const u16* Wt, const float* bias,
                      float* C, u16* Cb, int M, int K, int flags) {
        dim3 grid((M + GTM - 1) / GTM, 2);
        gemm_a16<<<grid, dim3(256), 0, stream>>>(A, Wt, bias, C, Cb, M, K, flags);
    };
    auto gemmcat = [&](const u16* A0, const u16* A1, const u16* A2, const u16* Wt,
                       const float* bias, u16* Cb, int M, int K, int flags) {
        dim3 grid((M + GTM - 1) / GTM, 2);
        gemm_cat<<<grid, dim3(256), 0, stream>>>(A0, A1, A2, Wt, bias, nullptr, Cb,
                                                 M, K, flags);
    };
    auto pack = [&](const float* W, const float* Wadd, u16* o, int Kpart) {
        pack_wt<<<(256 * Kpart + 255) / 256, 256, 0, stream>>>(W, Wadd, o, Kpart, Kpart, 0);
    };
    auto pack_at = [&](const float* W, const float* Wadd, u16* o, int Kpart, int Ktot, int koff) {
        pack_wt<<<(256 * Kpart + 255) / 256, 256, 0, stream>>>(W, Wadd, o, Kpart, Ktot, koff);
    };
    auto cvt = [&](const float* in, u16* o, size_t nelem) {
        long long n8 = (long long)(nelem / 8);
        int nb = (int)((n8 + 255) / 256); if (nb > 2048) nb = 2048;
        cvt_b16<<<nb, 256, 0, stream>>>(in, o, n8);
    };

    // ---- weight packing ----
    pack(W_ps, nullptr, wt_ps, 768);
    pack(W_pn, nullptr, wt_pn, 768);
    pack(W_pc, nullptr, wt_pc, 768);
    u16* wt_cs[2] = {wt_cs_a, wt_cs_b};
    u16* wt_cn[2] = {wt_cn_a, wt_cn_b};
    float* bsum[2] = {bsum0, bsum1};
    for (int l = 0; l < L; ++l) {
        const float* Wl = conv_Wl + (size_t)l * 3 * HH;
        const float* bl = conv_bl + (size_t)l * 3 * H;
        const float* Wr = conv_Wr + (size_t)l * 3 * HH;
        // xs fused: [m_ss | m_ns | xs] @ [Wl_ss ; Wl_ns ; Wr_ss+Wr_ns]
        pack_at(Wl,          nullptr,     wt_cs[l], 256, 768, 0);
        pack_at(Wl + 2 * HH, nullptr,     wt_cs[l], 256, 768, 256);
        pack_at(Wr,          Wr + 2 * HH, wt_cs[l], 256, 768, 512);
        // xn fused: [m_sn | xn] @ [Wl_sn ; Wr_sn]
        pack_at(Wl + HH,     nullptr,     wt_cn[l], 256, 512, 0);
        pack_at(Wr + HH,     nullptr,     wt_cn[l], 256, 512, 256);
        vsum_bias<<<1, 256, 0, stream>>>(bl, bl + 2 * H, bsum[l], H);
    }
    pack(W_attc, nullptr, wt_attc, 256);
    pack(W1,     nullptr, wt_w1, 1024);

    // ---- degree counts + CSR ----
    hipMemsetAsync(cnt_ss, 0, (size_t)Ns * 4, stream);
    hipMemsetAsync(cnt_sn, 0, (size_t)Ne * 4, stream);
    hipMemsetAsync(cnt_ns, 0, (size_t)Ns * 4, stream);
    count_edges<<<(Ess + 255) / 256, 256, 0, stream>>>(dst_ss, Ess, cnt_ss);
    count_edges<<<(Esn + 255) / 256, 256, 0, stream>>>(dst_sn, Esn, cnt_sn);
    count_edges<<<(Ens + 255) / 256, 256, 0, stream>>>(dst_ns, Ens, cnt_ns);
    make_inv<<<(Ns + 255) / 256, 256, 0, stream>>>(cnt_ss, inv_ss, Ns);
    make_inv<<<(Ne + 255) / 256, 256, 0, stream>>>(cnt_sn, inv_sn, Ne);
    make_inv<<<(Ns + 255) / 256, 256, 0, stream>>>(cnt_ns, inv_ns, Ns);
    auto build_csr = [&](const int* src, const int* dst, int E, int Nd,
                         const int* cnt, int* rowptr, int* colidx) {
        int nb = (Nd + 255) / 256;
        scan1<<<nb, 256, 0, stream>>>(cnt, Nd, rowptr, bsums);
        scan2<<<1, 256, 0, stream>>>(bsums, nb);
        scan3<<<nb, 256, 0, stream>>>(rowptr, bsums, Nd);
        hipMemsetAsync(fillc, 0, (size_t)Nd * 4, stream);
        csr_fill<<<(E + 255) / 256, 256, 0, stream>>>(src, dst, E, rowptr, fillc, colidx);
    };
    build_csr(src_ss, dst_ss, Ess, Ns, cnt_ss, rp_ss, col_ss);
    build_csr(src_sn, dst_sn, Esn, Ne, cnt_sn, rp_sn, col_sn);
    build_csr(src_ns, dst_ns, Ens, Ns, cnt_ns, rp_ns, col_ns);

    batch_bounds<<<(Ns + 1 + 255) / 256, 256, 0, stream>>>(batch_s, Ns, B, rp_b);

    // ---- input projections, serialized through the shared region RB ----
    cvt(x_s, x_s16, (size_t)Ns * 768);
    gemm16(x_s16, wt_ps, b_ps, nullptr, xs_a, Ns, 768, F_RELU | F_OUTB | F_NOC);
    cvt(x_n, x_n16, (size_t)Ne * 768);                      // reuses RB after x_s proj
    gemm16(x_n16, wt_pn, b_pn, nullptr, xn_a, Ne, 768, F_RELU | F_OUTB | F_NOC);
    cvt(claim, claim16, (size_t)B * 768);
    gemm16(claim16, wt_pc, b_pc, ch, ch_b, B, 768, F_RELU | F_OUTB);

    // ---- GNN layers: 3 gathers + 2 fused K-concat GEMMs per layer ----
    u16* xs_cur = xs_a; u16* xs_nxt = xs_b;
    u16* xn_cur = xn_a; u16* xn_nxt = xn_b;
    for (int l = 0; l < L; ++l) {
        const float* bl = conv_bl + (size_t)l * 3 * H;

        gather_mean_b16<<<(unsigned)(((long long)Ns * 64 + 255) / 256), 256, 0, stream>>>(
            xs_cur, rp_ss, col_ss, inv_ss, mA, Ns);
        gather_mean_b16<<<(unsigned)(((long long)Ns * 64 + 255) / 256), 256, 0, stream>>>(
            xn_cur, rp_ns, col_ns, inv_ns, mB, Ns);
        gemmcat(mA, mB, xs_cur, wt_cs[l], bsum[l], xs_nxt, Ns, 768,
                F_RELU | F_OUTB | F_NOC);

        gather_mean_b16<<<(unsigned)(((long long)Ne * 64 + 255) / 256), 256, 0, stream>>>(
            xs_cur, rp_sn, col_sn, inv_sn, mA, Ne);
        gemmcat(mA, xn_cur, nullptr, wt_cn[l], bl + H, xn_nxt, Ne, 512,
                F_RELU | F_OUTB | F_NOC);

        u16* t;
        t = xs_cur; xs_cur = xs_nxt; xs_nxt = t;
        t = xn_cur; xn_cur = xn_nxt; xn_nxt = t;
    }

    // ---- attentive pooling (reassociated: scores = xs · (c_att @ Ws^T)[batch]) ----
    gemm16(ch_b, wt_attc, nullptr, c_att, nullptr, B, 256, 0);
    att_u<<<B, 256, 0, stream>>>(c_att, W_atts, Uatt);
    scores2_kernel<<<(unsigned)(((long long)Ns * 64 + 255) / 256), 256, 0, stream>>>(
        xs_cur, Uatt, batch_s, scores, Ns);
    pool_softmax<<<B, 256, 0, stream>>>(scores, rp_b, invd);
    wsum_kernel<<<dim3(B, 4), 256, 0, stream>>>(scores, invd, xs_cur, rp_b, g);

    // ---- head MLP ----
    z_kernel<<<(B * H + 255) / 256, 256, 0, stream>>>(ch, g, z, B, H);
    gemm32(z, wt_w1, b1, hbuf, nullptr, B, 1024, F_RELU);
    out_kernel<<<(B * 2 + 255) / 256, 256, 0, stream>>>(hbuf, W2, b2, (float*)d_out, B, 256);
}